// Round 2
// baseline (2657.215 us; speedup 1.0000x reference)
//
#include <hip/hip_runtime.h>

typedef unsigned short u16;

__device__ __forceinline__ float bf2f(u16 u){
  union { unsigned int i; float f; } v; v.i = ((unsigned int)u) << 16; return v.f;
}
__device__ __forceinline__ u16 f2bf(float f){
  union { float f; unsigned int i; } v; v.f = f;
  unsigned int lsb = (v.i >> 16) & 1u;
  v.i += 0x7fffu + lsb;
  return (u16)(v.i >> 16);
}

// ---------------- dtype sniffer ----------------
// If the buffer holds fp32, even-indexed u16s are low mantissa bits (uniform
// random) -> bf16 exponent field uniform -> ~14% land in [100,135].
// If it holds bf16 N(0,1) data -> ~100% land there. flag=1 means fp32.
__global__ void k_sniff(const u16* __restrict__ p, int* __restrict__ flag){
  __shared__ int s[256];
  int tid = threadIdx.x;
  u16 v = p[2 * tid];
  int e = (v >> 7) & 0xFF;
  s[tid] = (e >= 100 && e <= 135) ? 1 : 0;
  __syncthreads();
  for (int off = 128; off; off >>= 1){
    if (tid < off) s[tid] += s[tid + off];
    __syncthreads();
  }
  if (tid == 0) *flag = (s[0] < 180) ? 1 : 0;
}
// canonicalize any float tensor to bf16
__global__ void k_canon(const void* __restrict__ src, u16* __restrict__ dst,
                        int n, const int* __restrict__ flag){
  int i = blockIdx.x * 256 + threadIdx.x;
  if (i < n){
    if (*flag) dst[i] = f2bf(((const float*)src)[i]);
    else       dst[i] = ((const u16*)src)[i];
  }
}

// ---------------- CSR build ----------------
__global__ void k_zero(int* __restrict__ p, int n){
  int i = blockIdx.x * 256 + threadIdx.x;
  if (i < n) p[i] = 0;
}
__global__ void k_hist(const int* __restrict__ dst, int* __restrict__ cnt, int E){
  int i = blockIdx.x * 256 + threadIdx.x;
  if (i < E) atomicAdd(&cnt[dst[i]], 1);
}
__global__ void k_scan1(const int* __restrict__ cnt, int* __restrict__ rowptr,
                        int* __restrict__ bsums, int N){
  __shared__ int s[256];
  int i = blockIdx.x * 256 + threadIdx.x;
  int v = (i < N) ? cnt[i] : 0;
  s[threadIdx.x] = v; __syncthreads();
  for (int off = 1; off < 256; off <<= 1){
    int x = 0;
    if (threadIdx.x >= off) x = s[threadIdx.x - off];
    __syncthreads();
    s[threadIdx.x] += x;
    __syncthreads();
  }
  if (i < N) rowptr[i + 1] = s[threadIdx.x];
  if (threadIdx.x == 255) bsums[blockIdx.x] = s[255];
}
__global__ void k_scan2(int* __restrict__ bsums, int nb){
  __shared__ int s[256];
  int t = threadIdx.x;
  int v = (t < nb) ? bsums[t] : 0;
  s[t] = v; __syncthreads();
  for (int off = 1; off < 256; off <<= 1){
    int x = 0;
    if (t >= off) x = s[t - off];
    __syncthreads();
    s[t] += x;
    __syncthreads();
  }
  if (t < nb) bsums[t] = s[t] - v;                // exclusive
}
__global__ void k_scan3(int* __restrict__ rowptr, const int* __restrict__ bsums,
                        int* __restrict__ cursor, int N){
  int i = blockIdx.x * 256 + threadIdx.x;
  if (i < N){
    int v = rowptr[i + 1] + bsums[blockIdx.x];
    rowptr[i + 1] = v;
    if (i + 1 < N) cursor[i + 1] = v;
    if (i == 0){ rowptr[0] = 0; cursor[0] = 0; }
  }
}
__global__ void k_scatter(const int* __restrict__ src, const int* __restrict__ dst,
                          int* __restrict__ cursor, int* __restrict__ csr_src, int E){
  int i = blockIdx.x * 256 + threadIdx.x;
  if (i < E){
    int p = atomicAdd(&cursor[dst[i]], 1);
    csr_src[p] = src[i];
  }
}

// ---------------- simple, certainly-correct GEMM ----------------
// OUT[n][c] = sum_k X[n][k] * W[k][c].  One block per node, thread c = out col.
// W reads are coalesced (consecutive c), X row staged in LDS.
__global__ __launch_bounds__(256) void simple_gemm(
    const u16* __restrict__ X, const u16* __restrict__ W,
    u16* __restrict__ OUT, int K)
{
  __shared__ float xr[256];
  const int n = blockIdx.x;
  for (int k = threadIdx.x; k < K; k += 256) xr[k] = bf2f(X[(size_t)n * K + k]);
  __syncthreads();
  const int c = threadIdx.x;
  float acc = 0.f;
  for (int k = 0; k < K; ++k)
    acc += xr[k] * bf2f(W[(size_t)k * 256 + c]);
  OUT[(size_t)n * 256 + c] = f2bf(acc);
}

// ---------------- per-node attention logits el/er ----------------
__global__ __launch_bounds__(256) void node_attn(
    const u16* __restrict__ ft, const u16* __restrict__ al, const u16* __restrict__ ar,
    float* __restrict__ el, float* __restrict__ er)
{
  int n = blockIdx.x;
  int c = threadIdx.x;                    // c = h*64+d, wave == head
  float v = bf2f(ft[(size_t)n * 256 + c]);
  float a = v * bf2f(al[c]);
  float b = v * bf2f(ar[c]);
  #pragma unroll
  for (int mm = 1; mm < 64; mm <<= 1){ a += __shfl_xor(a, mm); b += __shfl_xor(b, mm); }
  if ((c & 63) == 0){
    el[n * 4 + (c >> 6)] = a;
    er[n * 4 + (c >> 6)] = b;
  }
}

// ---------------- edge-softmax aggregation (1 block = 1 dst, 1 wave = 1 head) ----
__global__ __launch_bounds__(256) void aggregate(
    const u16* __restrict__ ft, const float* __restrict__ el, const float* __restrict__ er,
    const int* __restrict__ rowptr, const int* __restrict__ csr_src,
    const u16* __restrict__ residb, u16* __restrict__ outb,
    float* __restrict__ hf, int do_hf)
{
  const int d = blockIdx.x;
  const int tid = threadIdx.x;
  const int h = tid >> 6;
  const int lane = tid & 63;
  const int beg = rowptr[d];
  const int deg = rowptr[d + 1] - beg;
  float acc = 0.f;
  if (deg > 0){
    const float erh = er[d * 4 + h];
    float pm = -3.0e38f;
    for (int j = lane; j < deg; j += 64){
      int s = csr_src[beg + j];
      float e = el[s * 4 + h] + erh;
      e = (e > 0.f) ? e : 0.2f * e;
      pm = fmaxf(pm, e);
    }
    #pragma unroll
    for (int mm = 1; mm < 64; mm <<= 1) pm = fmaxf(pm, __shfl_xor(pm, mm));
    float pd = 0.f;
    for (int j = lane; j < deg; j += 64){
      int s = csr_src[beg + j];
      float e = el[s * 4 + h] + erh;
      e = (e > 0.f) ? e : 0.2f * e;
      pd += __expf(e - pm);
    }
    #pragma unroll
    for (int mm = 1; mm < 64; mm <<= 1) pd += __shfl_xor(pd, mm);
    const float inv = 1.f / pd;
    for (int j0 = 0; j0 < deg; j0 += 64){
      int j = j0 + lane;
      float a = 0.f; int s = 0;
      if (j < deg){
        s = csr_src[beg + j];
        float e = el[s * 4 + h] + erh;
        e = (e > 0.f) ? e : 0.2f * e;
        a = __expf(e - pm) * inv;
      }
      int lim = min(64, deg - j0);
      for (int jj = 0; jj < lim; ++jj){
        float aj = __shfl(a, jj);
        int   sj = __shfl(s, jj);
        acc += aj * bf2f(ft[(size_t)sj * 256 + h * 64 + lane]);   // 128B coalesced/wave
      }
    }
  }
  float o = acc + bf2f(residb[(size_t)d * 256 + tid]);
  if (!do_hf){
    o = fmaxf(o, 0.f);
    outb[(size_t)d * 256 + tid] = f2bf(o);
  } else {
    __shared__ float sh[256];
    sh[tid] = o;
    __syncthreads();
    if (tid < 64){
      hf[(size_t)d * 64 + tid] =
          0.25f * (sh[tid] + sh[tid + 64] + sh[tid + 128] + sh[tid + 192]);
    }
  }
}

// ---------------- edge MLP scorer (1 wave = 1 edge) ----------------
__global__ __launch_bounds__(256) void edge_mlp(
    const float* __restrict__ hf, const int* __restrict__ src, const int* __restrict__ dst,
    const u16* __restrict__ Wm1, const u16* __restrict__ bm1,
    const u16* __restrict__ Wm2, const u16* __restrict__ bm2,
    void* __restrict__ out, int E, const int* __restrict__ flag)
{
  __shared__ float w[64 * 64];
  for (int i = threadIdx.x; i < 64 * 64; i += 256) w[i] = bf2f(Wm1[i]);
  __syncthreads();
  const int is_f32 = *flag;
  const int lane = threadIdx.x & 63;
  const float b1 = bf2f(bm1[lane]);
  const float w2 = bf2f(Wm2[lane]);
  const float b2 = bf2f(bm2[0]);
  int wid = blockIdx.x * 4 + (threadIdx.x >> 6);
  int nw  = gridDim.x * 4;
  for (int e = wid; e < E; e += nw){
    int s = src[e], d = dst[e];
    float diff = fabsf(hf[(size_t)s * 64 + lane] - hf[(size_t)d * 64 + lane]);
    float z = b1;
    #pragma unroll
    for (int k = 0; k < 64; ++k)
      z += __shfl(diff, k) * w[k * 64 + lane];
    z = fmaxf(z, 0.f);
    float t = z * w2;
    #pragma unroll
    for (int mm = 1; mm < 64; mm <<= 1) t += __shfl_xor(t, mm);
    if (lane == 0){
      float sc = 1.f / (1.f + __expf(-(t + b2)));
      if (is_f32) ((float*)out)[e] = sc;
      else        ((u16*)out)[e]   = f2bf(sc);
    }
  }
}

extern "C" void kernel_launch(void* const* d_in, const int* in_sizes, int n_in,
                              void* d_out, int out_size, void* d_ws, size_t ws_size,
                              hipStream_t stream)
{
  const int* src = (const int*)d_in[1];
  const int* dst = (const int*)d_in[2];

  const int N = in_sizes[0] / 128;
  const int E = in_sizes[1];

  char* p = (char*)d_ws;
  auto alloc = [&](size_t bytes) -> char* {
    char* r = p; p += (bytes + 255) & ~(size_t)255; return r;
  };
  int* flag   = (int*)  alloc(4);
  u16* hc     = (u16*)  alloc((size_t)N * 128 * 2);
  u16* FT     = (u16*)  alloc((size_t)N * 256 * 2);
  u16* XA     = (u16*)  alloc((size_t)N * 256 * 2);
  u16* XB     = (u16*)  alloc((size_t)N * 256 * 2);
  float* el   = (float*)alloc((size_t)N * 4 * 4);
  float* er   = (float*)alloc((size_t)N * 4 * 4);
  float* hfb  = (float*)alloc((size_t)N * 64 * 4);
  int* rowptr = (int*)  alloc((size_t)(N + 1) * 4);
  int* cursor = (int*)  alloc((size_t)N * 4);
  int* csr    = (int*)  alloc((size_t)E * 4);
  int* bsums  = (int*)  alloc(1024);
  u16* W1c    = (u16*)  alloc(128 * 256 * 2);
  u16* Wr1c   = (u16*)  alloc(128 * 256 * 2);
  u16* W2c    = (u16*)  alloc(256 * 256 * 2);
  u16* W3c    = (u16*)  alloc(256 * 256 * 2);
  u16* al1c   = (u16*)  alloc(256 * 2);
  u16* ar1c   = (u16*)  alloc(256 * 2);
  u16* al2c   = (u16*)  alloc(256 * 2);
  u16* ar2c   = (u16*)  alloc(256 * 2);
  u16* al3c   = (u16*)  alloc(256 * 2);
  u16* ar3c   = (u16*)  alloc(256 * 2);
  u16* Wm1c   = (u16*)  alloc(4096 * 2);
  u16* bm1c   = (u16*)  alloc(64 * 2);
  u16* Wm2c   = (u16*)  alloc(64 * 2);
  u16* bm2c   = (u16*)  alloc(2);

  const int nb = (N + 255) / 256;
  const int ge = (E + 255) / 256;

  // dtype sniff + canonicalize all float tensors to bf16
  k_sniff<<<1, 256, 0, stream>>>((const u16*)d_in[0], flag);
  auto canon = [&](int idx, u16* dstp){
    int n = in_sizes[idx];
    k_canon<<<(n + 255) / 256, 256, 0, stream>>>(d_in[idx], dstp, n, flag);
  };
  canon(0, hc);
  canon(3, W1c);  canon(4, Wr1c);
  canon(5, al1c); canon(6, ar1c);
  canon(7, W2c);  canon(8, al2c);  canon(9, ar2c);
  canon(10, W3c); canon(11, al3c); canon(12, ar3c);
  canon(13, Wm1c); canon(14, bm1c); canon(15, Wm2c); canon(16, bm2c);

  // CSR by dst
  k_zero<<<nb, 256, 0, stream>>>(cursor, N);
  k_hist<<<ge, 256, 0, stream>>>(dst, cursor, E);
  k_scan1<<<nb, 256, 0, stream>>>(cursor, rowptr, bsums, N);
  k_scan2<<<1, 256, 0, stream>>>(bsums, nb);
  k_scan3<<<nb, 256, 0, stream>>>(rowptr, bsums, cursor, N);
  k_scatter<<<ge, 256, 0, stream>>>(src, dst, cursor, csr, E);

  // layer 1
  simple_gemm<<<N, 256, 0, stream>>>(hc, W1c, FT, 128);
  node_attn<<<N, 256, 0, stream>>>(FT, al1c, ar1c, el, er);
  simple_gemm<<<N, 256, 0, stream>>>(hc, Wr1c, XA, 128);
  aggregate<<<N, 256, 0, stream>>>(FT, el, er, rowptr, csr, XA, XB, nullptr, 0);
  // layer 2
  simple_gemm<<<N, 256, 0, stream>>>(XB, W2c, FT, 256);
  node_attn<<<N, 256, 0, stream>>>(FT, al2c, ar2c, el, er);
  aggregate<<<N, 256, 0, stream>>>(FT, el, er, rowptr, csr, XB, XA, nullptr, 0);
  // layer 3 (no activation, fused head-mean -> hf)
  simple_gemm<<<N, 256, 0, stream>>>(XA, W3c, FT, 256);
  node_attn<<<N, 256, 0, stream>>>(FT, al3c, ar3c, el, er);
  aggregate<<<N, 256, 0, stream>>>(FT, el, er, rowptr, csr, XA, nullptr, hfb, 1);
  // edge MLP
  edge_mlp<<<4096, 256, 0, stream>>>(hfb, src, dst, Wm1c, bm1c, Wm2c, bm2c,
                                     d_out, E, flag);
}

// Round 3
// 1231.440 us; speedup vs baseline: 2.1578x; 2.1578x over previous
//
#include <hip/hip_runtime.h>

typedef unsigned short u16;
typedef __attribute__((ext_vector_type(8))) short bf16x8;
typedef __attribute__((ext_vector_type(4))) float f32x4;

__device__ __forceinline__ float bf2f(u16 u){
  union { unsigned int i; float f; } v; v.i = ((unsigned int)u) << 16; return v.f;
}
__device__ __forceinline__ u16 f2bf(float f){
  union { float f; unsigned int i; } v; v.f = f;
  unsigned int lsb = (v.i >> 16) & 1u;
  v.i += 0x7fffu + lsb;
  return (u16)(v.i >> 16);
}

// ---------------- dtype sniffer ----------------
// fp32 buffer: even u16s are low mantissa bits -> exponent field uniform -> ~14%
// land in [100,135]. bf16 N(0,1): ~100%. flag=1 means fp32.
__global__ void k_sniff(const u16* __restrict__ p, int* __restrict__ flag){
  __shared__ int s[256];
  int tid = threadIdx.x;
  u16 v = p[2 * tid];
  int e = (v >> 7) & 0xFF;
  s[tid] = (e >= 100 && e <= 135) ? 1 : 0;
  __syncthreads();
  for (int off = 128; off; off >>= 1){
    if (tid < off) s[tid] += s[tid + off];
    __syncthreads();
  }
  if (tid == 0) *flag = (s[0] < 180) ? 1 : 0;
}
__global__ void k_canon(const void* __restrict__ src, u16* __restrict__ dst,
                        int n, const int* __restrict__ flag){
  int i = blockIdx.x * 256 + threadIdx.x;
  if (i < n){
    if (*flag) dst[i] = f2bf(((const float*)src)[i]);
    else       dst[i] = ((const u16*)src)[i];
  }
}

// ---------------- CSR build ----------------
__global__ void k_zero(int* __restrict__ p, int n){
  int i = blockIdx.x * 256 + threadIdx.x;
  if (i < n) p[i] = 0;
}
__global__ void k_hist(const int* __restrict__ dst, int* __restrict__ cnt, int E){
  int i = blockIdx.x * 256 + threadIdx.x;
  if (i < E) atomicAdd(&cnt[dst[i]], 1);
}
__global__ void k_scan1(const int* __restrict__ cnt, int* __restrict__ rowptr,
                        int* __restrict__ bsums, int N){
  __shared__ int s[256];
  int i = blockIdx.x * 256 + threadIdx.x;
  int v = (i < N) ? cnt[i] : 0;
  s[threadIdx.x] = v; __syncthreads();
  for (int off = 1; off < 256; off <<= 1){
    int x = 0;
    if (threadIdx.x >= off) x = s[threadIdx.x - off];
    __syncthreads();
    s[threadIdx.x] += x;
    __syncthreads();
  }
  if (i < N) rowptr[i + 1] = s[threadIdx.x];
  if (threadIdx.x == 255) bsums[blockIdx.x] = s[255];
}
__global__ void k_scan2(int* __restrict__ bsums, int nb){
  __shared__ int s[256];
  int t = threadIdx.x;
  int v = (t < nb) ? bsums[t] : 0;
  s[t] = v; __syncthreads();
  for (int off = 1; off < 256; off <<= 1){
    int x = 0;
    if (t >= off) x = s[t - off];
    __syncthreads();
    s[t] += x;
    __syncthreads();
  }
  if (t < nb) bsums[t] = s[t] - v;                // exclusive
}
__global__ void k_scan3(int* __restrict__ rowptr, const int* __restrict__ bsums,
                        int* __restrict__ cursor, int N){
  int i = blockIdx.x * 256 + threadIdx.x;
  if (i < N){
    int v = rowptr[i + 1] + bsums[blockIdx.x];
    rowptr[i + 1] = v;
    if (i + 1 < N) cursor[i + 1] = v;
    if (i == 0){ rowptr[0] = 0; cursor[0] = 0; }
  }
}
__global__ void k_scatter(const int* __restrict__ src, const int* __restrict__ dst,
                          int* __restrict__ cursor, int* __restrict__ csr_src, int E){
  int i = blockIdx.x * 256 + threadIdx.x;
  if (i < E){
    int p = atomicAdd(&cursor[dst[i]], 1);
    csr_src[p] = src[i];
  }
}
__global__ void k_transp(const u16* __restrict__ W, u16* __restrict__ WT, int K){
  int i = blockIdx.x * 256 + threadIdx.x;     // i over 256*K
  if (i < 256 * K){
    int c = i / K, k = i % K;
    WT[i] = W[(size_t)k * 256 + c];           // WT[c*K+k] = W[k][c]
  }
}

// ---------------- MFMA node GEMM: [N,K] bf16 x WT[256,K] -> [N,256] bf16 ------
// wave = 16 rows x 256 cols (16 tiles of 16x16x32), block = 64 rows.
__global__ __launch_bounds__(256) void mfma_gemm(
    const u16* __restrict__ X, const u16* __restrict__ WT,
    u16* __restrict__ OUT, int N, int K)
{
  const int wave = threadIdx.x >> 6;
  const int lane = threadIdx.x & 63;
  const int m = lane & 15;
  const int q = lane >> 4;
  const int row0 = blockIdx.x * 64 + wave * 16;
  f32x4 acc[16];
  #pragma unroll
  for (int t = 0; t < 16; ++t) acc[t] = (f32x4){0.f, 0.f, 0.f, 0.f};
  const int arow = row0 + m;
  const bool rvalid = arow < N;
  const u16* aptr = X + (size_t)arow * K + q * 8;
  for (int k0 = 0; k0 < K; k0 += 32){
    bf16x8 a = {};
    if (rvalid) a = *(const bf16x8*)(aptr + k0);
    #pragma unroll
    for (int t = 0; t < 16; ++t){
      const u16* bptr = WT + (size_t)(t * 16 + m) * K + k0 + q * 8;
      bf16x8 b = *(const bf16x8*)bptr;
      acc[t] = __builtin_amdgcn_mfma_f32_16x16x32_bf16(a, b, acc[t], 0, 0, 0);
    }
  }
  #pragma unroll
  for (int t = 0; t < 16; ++t){
    int col = t * 16 + m;
    #pragma unroll
    for (int r = 0; r < 4; ++r){
      int rr = row0 + q * 4 + r;
      if (rr < N) OUT[(size_t)rr * 256 + col] = f2bf(acc[t][r]);
    }
  }
}

// ---------------- per-node attention logits el/er ----------------
__global__ __launch_bounds__(256) void node_attn(
    const u16* __restrict__ ft, const u16* __restrict__ al, const u16* __restrict__ ar,
    float* __restrict__ el, float* __restrict__ er)
{
  int n = blockIdx.x;
  int c = threadIdx.x;                    // c = h*64+d, wave == head
  float v = bf2f(ft[(size_t)n * 256 + c]);
  float a = v * bf2f(al[c]);
  float b = v * bf2f(ar[c]);
  #pragma unroll
  for (int mm = 1; mm < 64; mm <<= 1){ a += __shfl_xor(a, mm); b += __shfl_xor(b, mm); }
  if ((c & 63) == 0){
    el[n * 4 + (c >> 6)] = a;
    er[n * 4 + (c >> 6)] = b;
  }
}

// ---------------- edge-softmax aggregation (1 block = 1 dst, 1 wave = 1 head) --
__global__ __launch_bounds__(256) void aggregate(
    const u16* __restrict__ ft, const float* __restrict__ el, const float* __restrict__ er,
    const int* __restrict__ rowptr, const int* __restrict__ csr_src,
    const u16* __restrict__ residb, u16* __restrict__ outb,
    u16* __restrict__ hf, int do_hf)
{
  const int d = blockIdx.x;
  const int tid = threadIdx.x;
  const int h = tid >> 6;
  const int lane = tid & 63;
  const int beg = rowptr[d];
  const int deg = rowptr[d + 1] - beg;
  float acc = 0.f;
  if (deg > 0){
    const float erh = er[d * 4 + h];
    float pm = -3.0e38f;
    for (int j = lane; j < deg; j += 64){
      int s = csr_src[beg + j];
      float e = el[s * 4 + h] + erh;
      e = (e > 0.f) ? e : 0.2f * e;
      pm = fmaxf(pm, e);
    }
    #pragma unroll
    for (int mm = 1; mm < 64; mm <<= 1) pm = fmaxf(pm, __shfl_xor(pm, mm));
    float pd = 0.f;
    for (int j = lane; j < deg; j += 64){
      int s = csr_src[beg + j];
      float e = el[s * 4 + h] + erh;
      e = (e > 0.f) ? e : 0.2f * e;
      pd += __expf(e - pm);
    }
    #pragma unroll
    for (int mm = 1; mm < 64; mm <<= 1) pd += __shfl_xor(pd, mm);
    const float inv = 1.f / pd;
    for (int j0 = 0; j0 < deg; j0 += 64){
      int j = j0 + lane;
      float a = 0.f; int s = 0;
      if (j < deg){
        s = csr_src[beg + j];
        float e = el[s * 4 + h] + erh;
        e = (e > 0.f) ? e : 0.2f * e;
        a = __expf(e - pm) * inv;
      }
      int lim = min(64, deg - j0);
      for (int jj = 0; jj < lim; ++jj){
        float aj = __shfl(a, jj);
        int   sj = __shfl(s, jj);
        acc += aj * bf2f(ft[(size_t)sj * 256 + h * 64 + lane]);   // 128B coalesced/wave
      }
    }
  }
  float o = acc + bf2f(residb[(size_t)d * 256 + tid]);
  if (!do_hf){
    o = fmaxf(o, 0.f);
    outb[(size_t)d * 256 + tid] = f2bf(o);
  } else {
    __shared__ float sh[256];
    sh[tid] = o;
    __syncthreads();
    if (tid < 64){
      hf[(size_t)d * 64 + tid] =
          f2bf(0.25f * (sh[tid] + sh[tid + 64] + sh[tid + 128] + sh[tid + 192]));
    }
  }
}

// ---------------- MFMA edge MLP: 1 wave = 16 edges/tile -----------------------
// z = relu(|hf[s]-hf[d]| @ Wm1 + b1); score = sigmoid(z @ Wm2 + b2)
__global__ __launch_bounds__(256) void edge_mlp_mfma(
    const u16* __restrict__ hfb,                       // [N,64] bf16
    const int* __restrict__ src, const int* __restrict__ dst,
    const u16* __restrict__ Wm1, const u16* __restrict__ bm1,
    const u16* __restrict__ Wm2, const u16* __restrict__ bm2,
    void* __restrict__ out, int E, const int* __restrict__ flag)
{
  const int lane = threadIdx.x & 63;
  const int m = lane & 15;
  const int q = lane >> 4;
  const int is_f32 = *flag;

  // B fragments for Wm1 (held in registers for the whole kernel):
  // col-tile t: n = t*16+m ; k-step ks: k = ks*32 + q*8 + j ; B[n][k]=Wm1[k*64+n]
  bf16x8 bfr[4][2];
  #pragma unroll
  for (int t = 0; t < 4; ++t)
    #pragma unroll
    for (int ks = 0; ks < 2; ++ks)
      #pragma unroll
      for (int j = 0; j < 8; ++j)
        bfr[t][ks][j] = (short)Wm1[(size_t)(ks * 32 + q * 8 + j) * 64 + t * 16 + m];

  float b1v[4], w2v[4];
  #pragma unroll
  for (int t = 0; t < 4; ++t){
    b1v[t] = bf2f(bm1[t * 16 + m]);
    w2v[t] = bf2f(Wm2[t * 16 + m]);
  }
  const float b2 = bf2f(bm2[0]);

  const int wid = blockIdx.x * 4 + (threadIdx.x >> 6);
  const int nw  = gridDim.x * 4;
  for (int e0 = wid * 16; e0 < E; e0 += nw * 16){
    // A fragment: row m = edge e0+m, k = ks*32 + q*8 + j
    int e = e0 + m; if (e >= E) e = E - 1;
    const int s = src[e], d = dst[e];
    const u16* ps = hfb + (size_t)s * 64;
    const u16* pd = hfb + (size_t)d * 64;
    bf16x8 af[2];
    #pragma unroll
    for (int ks = 0; ks < 2; ++ks){
      bf16x8 vs = *(const bf16x8*)(ps + ks * 32 + q * 8);
      bf16x8 vd = *(const bf16x8*)(pd + ks * 32 + q * 8);
      #pragma unroll
      for (int j = 0; j < 8; ++j)
        af[ks][j] = (short)f2bf(fabsf(bf2f((u16)vs[j]) - bf2f((u16)vd[j])));
    }
    f32x4 acc[4];
    #pragma unroll
    for (int t = 0; t < 4; ++t) acc[t] = (f32x4){0.f, 0.f, 0.f, 0.f};
    #pragma unroll
    for (int ks = 0; ks < 2; ++ks)
      #pragma unroll
      for (int t = 0; t < 4; ++t)
        acc[t] = __builtin_amdgcn_mfma_f32_16x16x32_bf16(af[ks], bfr[t][ks], acc[t], 0, 0, 0);
    // epilogue: lane holds z for edges (q*4+r), cols (t*16+m)
    #pragma unroll
    for (int r = 0; r < 4; ++r){
      float p = 0.f;
      #pragma unroll
      for (int t = 0; t < 4; ++t)
        p += fmaxf(acc[t][r] + b1v[t], 0.f) * w2v[t];
      #pragma unroll
      for (int mm = 1; mm < 16; mm <<= 1) p += __shfl_xor(p, mm);   // sum over m
      int er = e0 + q * 4 + r;
      if (m == 0 && er < E){
        float sc = 1.f / (1.f + __expf(-(p + b2)));
        if (is_f32) ((float*)out)[er] = sc;
        else        ((u16*)out)[er]   = f2bf(sc);
      }
    }
  }
}

extern "C" void kernel_launch(void* const* d_in, const int* in_sizes, int n_in,
                              void* d_out, int out_size, void* d_ws, size_t ws_size,
                              hipStream_t stream)
{
  const int* src = (const int*)d_in[1];
  const int* dst = (const int*)d_in[2];

  const int N = in_sizes[0] / 128;
  const int E = in_sizes[1];

  char* p = (char*)d_ws;
  auto alloc = [&](size_t bytes) -> char* {
    char* r = p; p += (bytes + 255) & ~(size_t)255; return r;
  };
  int* flag   = (int*)  alloc(4);
  u16* hc     = (u16*)  alloc((size_t)N * 128 * 2);
  u16* FT     = (u16*)  alloc((size_t)N * 256 * 2);
  u16* XA     = (u16*)  alloc((size_t)N * 256 * 2);
  u16* XB     = (u16*)  alloc((size_t)N * 256 * 2);
  float* el   = (float*)alloc((size_t)N * 4 * 4);
  float* er   = (float*)alloc((size_t)N * 4 * 4);
  u16* hfb    = (u16*)  alloc((size_t)N * 64 * 2);
  int* rowptr = (int*)  alloc((size_t)(N + 1) * 4);
  int* cursor = (int*)  alloc((size_t)N * 4);
  int* csr    = (int*)  alloc((size_t)E * 4);
  int* bsums  = (int*)  alloc(1024);
  u16* W1c    = (u16*)  alloc(128 * 256 * 2);
  u16* Wr1c   = (u16*)  alloc(128 * 256 * 2);
  u16* W2c    = (u16*)  alloc(256 * 256 * 2);
  u16* W3c    = (u16*)  alloc(256 * 256 * 2);
  u16* WT1    = (u16*)  alloc(128 * 256 * 2);
  u16* WTr1   = (u16*)  alloc(128 * 256 * 2);
  u16* WT2    = (u16*)  alloc(256 * 256 * 2);
  u16* WT3    = (u16*)  alloc(256 * 256 * 2);
  u16* al1c   = (u16*)  alloc(256 * 2);
  u16* ar1c   = (u16*)  alloc(256 * 2);
  u16* al2c   = (u16*)  alloc(256 * 2);
  u16* ar2c   = (u16*)  alloc(256 * 2);
  u16* al3c   = (u16*)  alloc(256 * 2);
  u16* ar3c   = (u16*)  alloc(256 * 2);
  u16* Wm1c   = (u16*)  alloc(4096 * 2);
  u16* bm1c   = (u16*)  alloc(64 * 2);
  u16* Wm2c   = (u16*)  alloc(64 * 2);
  u16* bm2c   = (u16*)  alloc(2);

  const int nb = (N + 255) / 256;
  const int ge = (E + 255) / 256;

  // dtype sniff + canonicalize all float tensors to bf16
  k_sniff<<<1, 256, 0, stream>>>((const u16*)d_in[0], flag);
  auto canon = [&](int idx, u16* dstp){
    int n = in_sizes[idx];
    k_canon<<<(n + 255) / 256, 256, 0, stream>>>(d_in[idx], dstp, n, flag);
  };
  canon(0, hc);
  canon(3, W1c);  canon(4, Wr1c);
  canon(5, al1c); canon(6, ar1c);
  canon(7, W2c);  canon(8, al2c);  canon(9, ar2c);
  canon(10, W3c); canon(11, al3c); canon(12, ar3c);
  canon(13, Wm1c); canon(14, bm1c); canon(15, Wm2c); canon(16, bm2c);

  // CSR by dst
  k_zero<<<nb, 256, 0, stream>>>(cursor, N);
  k_hist<<<ge, 256, 0, stream>>>(dst, cursor, E);
  k_scan1<<<nb, 256, 0, stream>>>(cursor, rowptr, bsums, N);
  k_scan2<<<1, 256, 0, stream>>>(bsums, nb);
  k_scan3<<<nb, 256, 0, stream>>>(rowptr, bsums, cursor, N);
  k_scatter<<<ge, 256, 0, stream>>>(src, dst, cursor, csr, E);

  // weight transposes for k-contiguous MFMA B-fragments
  k_transp<<<(256 * 128 + 255) / 256, 256, 0, stream>>>(W1c, WT1, 128);
  k_transp<<<(256 * 128 + 255) / 256, 256, 0, stream>>>(Wr1c, WTr1, 128);
  k_transp<<<(256 * 256 + 255) / 256, 256, 0, stream>>>(W2c, WT2, 256);
  k_transp<<<(256 * 256 + 255) / 256, 256, 0, stream>>>(W3c, WT3, 256);

  const int gA = (N + 63) / 64;
  // layer 1
  mfma_gemm<<<gA, 256, 0, stream>>>(hc, WT1, FT, N, 128);
  node_attn<<<N, 256, 0, stream>>>(FT, al1c, ar1c, el, er);
  mfma_gemm<<<gA, 256, 0, stream>>>(hc, WTr1, XA, N, 128);
  aggregate<<<N, 256, 0, stream>>>(FT, el, er, rowptr, csr, XA, XB, nullptr, 0);
  // layer 2
  mfma_gemm<<<gA, 256, 0, stream>>>(XB, WT2, FT, N, 256);
  node_attn<<<N, 256, 0, stream>>>(FT, al2c, ar2c, el, er);
  aggregate<<<N, 256, 0, stream>>>(FT, el, er, rowptr, csr, XB, XA, nullptr, 0);
  // layer 3 (fused head-mean -> hf bf16)
  mfma_gemm<<<gA, 256, 0, stream>>>(XA, WT3, FT, N, 256);
  node_attn<<<N, 256, 0, stream>>>(FT, al3c, ar3c, el, er);
  aggregate<<<N, 256, 0, stream>>>(FT, el, er, rowptr, csr, XA, nullptr, hfb, 1);
  // edge MLP (MFMA)
  edge_mlp_mfma<<<2048, 256, 0, stream>>>(hfb, src, dst, Wm1c, bm1c, Wm2c, bm2c,
                                          d_out, E, flag);
}

// Round 4
// 843.601 us; speedup vs baseline: 3.1498x; 1.4597x over previous
//
#include <hip/hip_runtime.h>

typedef unsigned short u16;
typedef __attribute__((ext_vector_type(8))) short bf16x8;
typedef __attribute__((ext_vector_type(4))) float f32x4;

__device__ __forceinline__ float bf2f(u16 u){
  union { unsigned int i; float f; } v; v.i = ((unsigned int)u) << 16; return v.f;
}
__device__ __forceinline__ u16 f2bf(float f){
  union { float f; unsigned int i; } v; v.f = f;
  unsigned int lsb = (v.i >> 16) & 1u;
  v.i += 0x7fffu + lsb;
  return (u16)(v.i >> 16);
}

// ---------------- dtype sniffer ----------------
__global__ void k_sniff(const u16* __restrict__ p, int* __restrict__ flag){
  __shared__ int s[256];
  int tid = threadIdx.x;
  u16 v = p[2 * tid];
  int e = (v >> 7) & 0xFF;
  s[tid] = (e >= 100 && e <= 135) ? 1 : 0;
  __syncthreads();
  for (int off = 128; off; off >>= 1){
    if (tid < off) s[tid] += s[tid + off];
    __syncthreads();
  }
  if (tid == 0) *flag = (s[0] < 180) ? 1 : 0;
}
__global__ void k_canon(const void* __restrict__ src, u16* __restrict__ dst,
                        int n, const int* __restrict__ flag){
  int i = blockIdx.x * 256 + threadIdx.x;
  if (i < n){
    if (*flag) dst[i] = f2bf(((const float*)src)[i]);
    else       dst[i] = ((const u16*)src)[i];
  }
}
struct CanonEnt { const void* s; u16* d; int n; };
struct Canon10 { CanonEnt e[10]; };
__global__ void k_canon10(Canon10 c, const int* __restrict__ flag){
  CanonEnt en = c.e[blockIdx.y];
  int i = blockIdx.x * 256 + threadIdx.x;
  if (i < en.n){
    if (*flag) en.d[i] = f2bf(((const float*)en.s)[i]);
    else       en.d[i] = ((const u16*)en.s)[i];
  }
}
// canonicalize + transpose GEMM weights: W[K][256] -> WT[256][K]
struct CanonWEnt { const void* s; u16* wt; int K; };
struct CanonW4 { CanonWEnt e[4]; };
__global__ void k_canonw(CanonW4 c, const int* __restrict__ flag){
  CanonWEnt en = c.e[blockIdx.y];
  int i = blockIdx.x * 256 + threadIdx.x;
  if (i < 256 * en.K){
    int k = i >> 8, cc = i & 255;
    u16 b;
    if (*flag) b = f2bf(((const float*)en.s)[i]);
    else       b = ((const u16*)en.s)[i];
    en.wt[(size_t)cc * en.K + k] = b;
  }
}

// ---------------- CSR build ----------------
__global__ void k_zero(int* __restrict__ p, int n){
  int i = blockIdx.x * 256 + threadIdx.x;
  if (i < n) p[i] = 0;
}
__global__ void k_hist(const int* __restrict__ dst, int* __restrict__ cnt, int E){
  int i = blockIdx.x * 256 + threadIdx.x;
  if (i < E) atomicAdd(&cnt[dst[i]], 1);
}
__global__ void k_scan1(const int* __restrict__ cnt, int* __restrict__ rowptr,
                        int* __restrict__ bsums, int N){
  __shared__ int s[256];
  int i = blockIdx.x * 256 + threadIdx.x;
  int v = (i < N) ? cnt[i] : 0;
  s[threadIdx.x] = v; __syncthreads();
  for (int off = 1; off < 256; off <<= 1){
    int x = 0;
    if (threadIdx.x >= off) x = s[threadIdx.x - off];
    __syncthreads();
    s[threadIdx.x] += x;
    __syncthreads();
  }
  if (i < N) rowptr[i + 1] = s[threadIdx.x];
  if (threadIdx.x == 255) bsums[blockIdx.x] = s[255];
}
__global__ void k_scan2(int* __restrict__ bsums, int nb){
  __shared__ int s[256];
  int t = threadIdx.x;
  int v = (t < nb) ? bsums[t] : 0;
  s[t] = v; __syncthreads();
  for (int off = 1; off < 256; off <<= 1){
    int x = 0;
    if (t >= off) x = s[t - off];
    __syncthreads();
    s[t] += x;
    __syncthreads();
  }
  if (t < nb) bsums[t] = s[t] - v;                // exclusive
}
__global__ void k_scan3(int* __restrict__ rowptr, const int* __restrict__ bsums,
                        int* __restrict__ cursor, int N){
  int i = blockIdx.x * 256 + threadIdx.x;
  if (i < N){
    int v = rowptr[i + 1] + bsums[blockIdx.x];
    rowptr[i + 1] = v;
    if (i + 1 < N) cursor[i + 1] = v;
    if (i == 0){ rowptr[0] = 0; cursor[0] = 0; }
  }
}
__global__ void k_scatter(const int* __restrict__ src, const int* __restrict__ dst,
                          int* __restrict__ cursor, int* __restrict__ csr_src,
                          int* __restrict__ csr_dst, int E){
  int i = blockIdx.x * 256 + threadIdx.x;
  if (i < E){
    int p = atomicAdd(&cursor[dst[i]], 1);
    csr_src[p] = src[i];
    csr_dst[p] = dst[i];
  }
}

// ---------------- MFMA node GEMM: [N,K] bf16 x WT[256,K] -> [N,256] bf16 ------
__global__ __launch_bounds__(256) void mfma_gemm(
    const u16* __restrict__ X, const u16* __restrict__ WT,
    u16* __restrict__ OUT, int N, int K)
{
  const int wave = threadIdx.x >> 6;
  const int lane = threadIdx.x & 63;
  const int m = lane & 15;
  const int q = lane >> 4;
  const int row0 = blockIdx.x * 64 + wave * 16;
  f32x4 acc[16];
  #pragma unroll
  for (int t = 0; t < 16; ++t) acc[t] = (f32x4){0.f, 0.f, 0.f, 0.f};
  const int arow = row0 + m;
  const bool rvalid = arow < N;
  const u16* aptr = X + (size_t)arow * K + q * 8;
  for (int k0 = 0; k0 < K; k0 += 32){
    bf16x8 a = {};
    if (rvalid) a = *(const bf16x8*)(aptr + k0);
    #pragma unroll
    for (int t = 0; t < 16; ++t){
      const u16* bptr = WT + (size_t)(t * 16 + m) * K + k0 + q * 8;
      bf16x8 b = *(const bf16x8*)bptr;
      acc[t] = __builtin_amdgcn_mfma_f32_16x16x32_bf16(a, b, acc[t], 0, 0, 0);
    }
  }
  #pragma unroll
  for (int t = 0; t < 16; ++t){
    int col = t * 16 + m;
    #pragma unroll
    for (int r = 0; r < 4; ++r){
      int rr = row0 + q * 4 + r;
      if (rr < N) OUT[(size_t)rr * 256 + col] = f2bf(acc[t][r]);
    }
  }
}

// ---------------- per-node attention logits el/er ----------------
__global__ __launch_bounds__(256) void node_attn(
    const u16* __restrict__ ft, const u16* __restrict__ al, const u16* __restrict__ ar,
    float* __restrict__ el, float* __restrict__ er)
{
  int n = blockIdx.x;
  int c = threadIdx.x;
  float v = bf2f(ft[(size_t)n * 256 + c]);
  float a = v * bf2f(al[c]);
  float b = v * bf2f(ar[c]);
  #pragma unroll
  for (int mm = 1; mm < 64; mm <<= 1){ a += __shfl_xor(a, mm); b += __shfl_xor(b, mm); }
  if ((c & 63) == 0){
    el[n * 4 + (c >> 6)] = a;
    er[n * 4 + (c >> 6)] = b;
  }
}

// ---------------- per-edge leaky logits, head-major, CSR order ----------------
__global__ void k_edge_logits(const int* __restrict__ csr_src, const int* __restrict__ csr_dst,
                              const float* __restrict__ el, const float* __restrict__ er,
                              float* __restrict__ leh, int E){
  int p = blockIdx.x * 256 + threadIdx.x;
  if (p < E){
    int s = csr_src[p], d = csr_dst[p];
    float4 a = ((const float4*)el)[s];
    float4 b = ((const float4*)er)[d];
    float e0 = a.x + b.x, e1 = a.y + b.y, e2 = a.z + b.z, e3 = a.w + b.w;
    leh[p]         = (e0 > 0.f) ? e0 : 0.2f * e0;
    leh[E + p]     = (e1 > 0.f) ? e1 : 0.2f * e1;
    leh[2 * E + p] = (e2 > 0.f) ? e2 : 0.2f * e2;
    leh[3 * E + p] = (e3 > 0.f) ? e3 : 0.2f * e3;
  }
}

// ---------------- aggregation v2: block-wide 16B/lane gather ------------------
// 1 block = 1 dst. Wave h does online softmax for head h from coalesced leh.
// Inner loop: thread t = (edge-slot t>>5, col-group t&31); 8 edges / iteration.
__global__ __launch_bounds__(256) void aggregate2(
    const u16* __restrict__ ft, const float* __restrict__ leh,
    const int* __restrict__ rowptr, const int* __restrict__ csr_src,
    const u16* __restrict__ residb, u16* __restrict__ outb,
    u16* __restrict__ hf, int do_hf, int E)
{
  __shared__ float sacc[8 * 256];
  __shared__ float salpha[64 * 4];
  __shared__ int   ssrc[64];
  const int d = blockIdx.x, tid = threadIdx.x;
  const int h = tid >> 6, lane = tid & 63;
  const int beg = rowptr[d], deg = rowptr[d + 1] - beg;
  const int r = tid >> 5, g = tid & 31, hg = g >> 3;
  float acc8[8];
  #pragma unroll
  for (int j = 0; j < 8; ++j) acc8[j] = 0.f;

  if (deg > 0){
    const float* lh = leh + (size_t)h * E + beg;
    float m = -3.0e38f, dn = 0.f, ecache = 0.f;
    if (deg <= 64){
      if (lane < deg){ ecache = lh[lane]; m = ecache; dn = 1.f; }
    } else {
      for (int j = lane; j < deg; j += 64){
        float e = lh[j];
        float nm = fmaxf(m, e);
        dn = dn * __expf(m - nm) + __expf(e - nm);
        m = nm;
      }
    }
    #pragma unroll
    for (int mm = 1; mm < 64; mm <<= 1){
      float om = __shfl_xor(m, mm), od = __shfl_xor(dn, mm);
      float nm = fmaxf(m, om);
      dn = dn * __expf(m - nm) + od * __expf(om - nm);
      m = nm;
    }
    const float inv = 1.f / dn;

    for (int c0 = 0; c0 < deg; c0 += 64){
      int cs = min(64, deg - c0);
      if (lane < cs){
        float e = (deg <= 64) ? ecache : lh[c0 + lane];
        salpha[lane * 4 + h] = __expf(e - m) * inv;
        if (h == 0) ssrc[lane] = csr_src[beg + c0 + lane];
      }
      __syncthreads();
      int nsub = (cs + 7) >> 3;
      for (int sub = 0; sub < nsub; ++sub){
        int je = sub * 8 + r;
        if (je < cs){
          int s = ssrc[je];
          float a = salpha[je * 4 + hg];
          bf16x8 v = *(const bf16x8*)(ft + (size_t)s * 256 + g * 8);
          #pragma unroll
          for (int j = 0; j < 8; ++j) acc8[j] += a * bf2f((u16)v[j]);
        }
      }
      __syncthreads();
    }
  }
  // reduce the 8 edge-slots
  #pragma unroll
  for (int j = 0; j < 8; ++j) sacc[r * 256 + g * 8 + j] = acc8[j];
  __syncthreads();
  float o = 0.f;
  #pragma unroll
  for (int rr = 0; rr < 8; ++rr) o += sacc[rr * 256 + tid];
  o += bf2f(residb[(size_t)d * 256 + tid]);
  if (!do_hf){
    outb[(size_t)d * 256 + tid] = f2bf(fmaxf(o, 0.f));
  } else {
    __syncthreads();
    sacc[tid] = o;
    __syncthreads();
    if (tid < 64)
      hf[(size_t)d * 64 + tid] =
          f2bf(0.25f * (sacc[tid] + sacc[tid + 64] + sacc[tid + 128] + sacc[tid + 192]));
  }
}

// ---------------- MFMA edge MLP: 1 wave = 16 edges/tile -----------------------
__global__ __launch_bounds__(256) void edge_mlp_mfma(
    const u16* __restrict__ hfb,
    const int* __restrict__ src, const int* __restrict__ dst,
    const u16* __restrict__ Wm1, const u16* __restrict__ bm1,
    const u16* __restrict__ Wm2, const u16* __restrict__ bm2,
    void* __restrict__ out, int E, const int* __restrict__ flag)
{
  const int lane = threadIdx.x & 63;
  const int m = lane & 15;
  const int q = lane >> 4;
  const int is_f32 = *flag;

  bf16x8 bfr[4][2];
  #pragma unroll
  for (int t = 0; t < 4; ++t)
    #pragma unroll
    for (int ks = 0; ks < 2; ++ks)
      #pragma unroll
      for (int j = 0; j < 8; ++j)
        bfr[t][ks][j] = (short)Wm1[(size_t)(ks * 32 + q * 8 + j) * 64 + t * 16 + m];

  float b1v[4], w2v[4];
  #pragma unroll
  for (int t = 0; t < 4; ++t){
    b1v[t] = bf2f(bm1[t * 16 + m]);
    w2v[t] = bf2f(Wm2[t * 16 + m]);
  }
  const float b2 = bf2f(bm2[0]);

  const int wid = blockIdx.x * 4 + (threadIdx.x >> 6);
  const int nw  = gridDim.x * 4;
  for (int e0 = wid * 16; e0 < E; e0 += nw * 16){
    int e = e0 + m; if (e >= E) e = E - 1;
    const int s = src[e], d = dst[e];
    const u16* ps = hfb + (size_t)s * 64;
    const u16* pd = hfb + (size_t)d * 64;
    bf16x8 af[2];
    #pragma unroll
    for (int ks = 0; ks < 2; ++ks){
      bf16x8 vs = *(const bf16x8*)(ps + ks * 32 + q * 8);
      bf16x8 vd = *(const bf16x8*)(pd + ks * 32 + q * 8);
      #pragma unroll
      for (int j = 0; j < 8; ++j)
        af[ks][j] = (short)f2bf(fabsf(bf2f((u16)vs[j]) - bf2f((u16)vd[j])));
    }
    f32x4 acc[4];
    #pragma unroll
    for (int t = 0; t < 4; ++t) acc[t] = (f32x4){0.f, 0.f, 0.f, 0.f};
    #pragma unroll
    for (int ks = 0; ks < 2; ++ks)
      #pragma unroll
      for (int t = 0; t < 4; ++t)
        acc[t] = __builtin_amdgcn_mfma_f32_16x16x32_bf16(af[ks], bfr[t][ks], acc[t], 0, 0, 0);
    #pragma unroll
    for (int r = 0; r < 4; ++r){
      float p = 0.f;
      #pragma unroll
      for (int t = 0; t < 4; ++t)
        p += fmaxf(acc[t][r] + b1v[t], 0.f) * w2v[t];
      #pragma unroll
      for (int mm = 1; mm < 16; mm <<= 1) p += __shfl_xor(p, mm);
      int er = e0 + q * 4 + r;
      if (m == 0 && er < E){
        float sc = 1.f / (1.f + __expf(-(p + b2)));
        if (is_f32) ((float*)out)[er] = sc;
        else        ((u16*)out)[er]   = f2bf(sc);
      }
    }
  }
}

extern "C" void kernel_launch(void* const* d_in, const int* in_sizes, int n_in,
                              void* d_out, int out_size, void* d_ws, size_t ws_size,
                              hipStream_t stream)
{
  const int* src = (const int*)d_in[1];
  const int* dst = (const int*)d_in[2];

  const int N = in_sizes[0] / 128;
  const int E = in_sizes[1];

  char* p = (char*)d_ws;
  auto alloc = [&](size_t bytes) -> char* {
    char* r = p; p += (bytes + 255) & ~(size_t)255; return r;
  };
  int* flag   = (int*)  alloc(4);
  u16* hc     = (u16*)  alloc((size_t)N * 128 * 2);
  u16* FT     = (u16*)  alloc((size_t)N * 256 * 2);
  u16* XA     = (u16*)  alloc((size_t)N * 256 * 2);
  u16* XB     = (u16*)  alloc((size_t)N * 256 * 2);
  float* el   = (float*)alloc((size_t)N * 4 * 4);
  float* er   = (float*)alloc((size_t)N * 4 * 4);
  float* leh  = (float*)alloc((size_t)E * 4 * 4);
  u16* hfb    = (u16*)  alloc((size_t)N * 64 * 2);
  int* rowptr = (int*)  alloc((size_t)(N + 1) * 4);
  int* cursor = (int*)  alloc((size_t)N * 4);
  int* csr    = (int*)  alloc((size_t)E * 4);
  int* csrd   = (int*)  alloc((size_t)E * 4);
  int* bsums  = (int*)  alloc(1024);
  u16* WT1    = (u16*)  alloc(128 * 256 * 2);
  u16* WTr1   = (u16*)  alloc(128 * 256 * 2);
  u16* WT2    = (u16*)  alloc(256 * 256 * 2);
  u16* WT3    = (u16*)  alloc(256 * 256 * 2);
  u16* al1c   = (u16*)  alloc(256 * 2);
  u16* ar1c   = (u16*)  alloc(256 * 2);
  u16* al2c   = (u16*)  alloc(256 * 2);
  u16* ar2c   = (u16*)  alloc(256 * 2);
  u16* al3c   = (u16*)  alloc(256 * 2);
  u16* ar3c   = (u16*)  alloc(256 * 2);
  u16* Wm1c   = (u16*)  alloc(4096 * 2);
  u16* bm1c   = (u16*)  alloc(64 * 2);
  u16* Wm2c   = (u16*)  alloc(64 * 2);
  u16* bm2c   = (u16*)  alloc(2);

  const int nb = (N + 255) / 256;
  const int ge = (E + 255) / 256;

  // dtype sniff + canonicalize
  k_sniff<<<1, 256, 0, stream>>>((const u16*)d_in[0], flag);
  k_canon<<<(N * 128 + 255) / 256, 256, 0, stream>>>(d_in[0], hc, N * 128, flag);
  {
    Canon10 c;
    c.e[0] = {d_in[5],  al1c, 256};  c.e[1] = {d_in[6],  ar1c, 256};
    c.e[2] = {d_in[8],  al2c, 256};  c.e[3] = {d_in[9],  ar2c, 256};
    c.e[4] = {d_in[11], al3c, 256};  c.e[5] = {d_in[12], ar3c, 256};
    c.e[6] = {d_in[13], Wm1c, 4096}; c.e[7] = {d_in[14], bm1c, 64};
    c.e[8] = {d_in[15], Wm2c, 64};   c.e[9] = {d_in[16], bm2c, 1};
    dim3 g((4096 + 255) / 256, 10);
    k_canon10<<<g, 256, 0, stream>>>(c, flag);
  }
  {
    CanonW4 c;
    c.e[0] = {d_in[3],  WT1,  128};  c.e[1] = {d_in[4],  WTr1, 128};
    c.e[2] = {d_in[7],  WT2,  256};  c.e[3] = {d_in[10], WT3,  256};
    dim3 g(256, 4);
    k_canonw<<<g, 256, 0, stream>>>(c, flag);
  }

  // CSR by dst
  k_zero<<<nb, 256, 0, stream>>>(cursor, N);
  k_hist<<<ge, 256, 0, stream>>>(dst, cursor, E);
  k_scan1<<<nb, 256, 0, stream>>>(cursor, rowptr, bsums, N);
  k_scan2<<<1, 256, 0, stream>>>(bsums, nb);
  k_scan3<<<nb, 256, 0, stream>>>(rowptr, bsums, cursor, N);
  k_scatter<<<ge, 256, 0, stream>>>(src, dst, cursor, csr, csrd, E);

  const int gA = (N + 63) / 64;
  // layer 1
  mfma_gemm<<<gA, 256, 0, stream>>>(hc, WT1, FT, N, 128);
  node_attn<<<N, 256, 0, stream>>>(FT, al1c, ar1c, el, er);
  mfma_gemm<<<gA, 256, 0, stream>>>(hc, WTr1, XA, N, 128);
  k_edge_logits<<<ge, 256, 0, stream>>>(csr, csrd, el, er, leh, E);
  aggregate2<<<N, 256, 0, stream>>>(FT, leh, rowptr, csr, XA, XB, nullptr, 0, E);
  // layer 2
  mfma_gemm<<<gA, 256, 0, stream>>>(XB, WT2, FT, N, 256);
  node_attn<<<N, 256, 0, stream>>>(FT, al2c, ar2c, el, er);
  k_edge_logits<<<ge, 256, 0, stream>>>(csr, csrd, el, er, leh, E);
  aggregate2<<<N, 256, 0, stream>>>(FT, leh, rowptr, csr, XB, XA, nullptr, 0, E);
  // layer 3 (fused head-mean -> hf bf16)
  mfma_gemm<<<gA, 256, 0, stream>>>(XA, WT3, FT, N, 256);
  node_attn<<<N, 256, 0, stream>>>(FT, al3c, ar3c, el, er);
  k_edge_logits<<<ge, 256, 0, stream>>>(csr, csrd, el, er, leh, E);
  aggregate2<<<N, 256, 0, stream>>>(FT, leh, rowptr, csr, XA, nullptr, hfb, 1, E);
  // edge MLP (MFMA)
  edge_mlp_mfma<<<2048, 256, 0, stream>>>(hfb, src, dst, Wm1c, bm1c, Wm2c, bm2c,
                                          d_out, E, flag);
}

// Round 5
// 702.903 us; speedup vs baseline: 3.7803x; 1.2002x over previous
//
#include <hip/hip_runtime.h>

typedef unsigned short u16;
typedef __attribute__((ext_vector_type(8))) short bf16x8;
typedef __attribute__((ext_vector_type(4))) float f32x4;

__device__ __forceinline__ float bf2f(u16 u){
  union { unsigned int i; float f; } v; v.i = ((unsigned int)u) << 16; return v.f;
}
__device__ __forceinline__ u16 f2bf(float f){
  union { float f; unsigned int i; } v; v.f = f;
  unsigned int lsb = (v.i >> 16) & 1u;
  v.i += 0x7fffu + lsb;
  return (u16)(v.i >> 16);
}

// ---------------- dtype sniffer ----------------
__global__ void k_sniff(const u16* __restrict__ p, int* __restrict__ flag){
  __shared__ int s[256];
  int tid = threadIdx.x;
  u16 v = p[2 * tid];
  int e = (v >> 7) & 0xFF;
  s[tid] = (e >= 100 && e <= 135) ? 1 : 0;
  __syncthreads();
  for (int off = 128; off; off >>= 1){
    if (tid < off) s[tid] += s[tid + off];
    __syncthreads();
  }
  if (tid == 0) *flag = (s[0] < 180) ? 1 : 0;
}
__global__ void k_canon(const void* __restrict__ src, u16* __restrict__ dst,
                        int n, const int* __restrict__ flag){
  int i = blockIdx.x * 256 + threadIdx.x;
  if (i < n){
    if (*flag) dst[i] = f2bf(((const float*)src)[i]);
    else       dst[i] = ((const u16*)src)[i];
  }
}
struct CanonEnt { const void* s; u16* d; int n; };
struct Canon10 { CanonEnt e[10]; };
__global__ void k_canon10(Canon10 c, const int* __restrict__ flag){
  CanonEnt en = c.e[blockIdx.y];
  int i = blockIdx.x * 256 + threadIdx.x;
  if (i < en.n){
    if (*flag) en.d[i] = f2bf(((const float*)en.s)[i]);
    else       en.d[i] = ((const u16*)en.s)[i];
  }
}
struct CanonWEnt { const void* s; u16* wt; int K; };
struct CanonW4 { CanonWEnt e[4]; };
__global__ void k_canonw(CanonW4 c, const int* __restrict__ flag){
  CanonWEnt en = c.e[blockIdx.y];
  int i = blockIdx.x * 256 + threadIdx.x;
  if (i < 256 * en.K){
    int k = i >> 8, cc = i & 255;
    u16 b;
    if (*flag) b = f2bf(((const float*)en.s)[i]);
    else       b = ((const u16*)en.s)[i];
    en.wt[(size_t)cc * en.K + k] = b;
  }
}

// ---------------- CSR build ----------------
__global__ void k_zero(int* __restrict__ p, int n){
  int i = blockIdx.x * 256 + threadIdx.x;
  if (i < n) p[i] = 0;
}
__global__ void k_hist(const int* __restrict__ dst, int* __restrict__ cnt, int E){
  int i = blockIdx.x * 256 + threadIdx.x;
  if (i < E) atomicAdd(&cnt[dst[i]], 1);
}
__global__ void k_scan1(const int* __restrict__ cnt, int* __restrict__ rowptr,
                        int* __restrict__ bsums, int N){
  __shared__ int s[256];
  int i = blockIdx.x * 256 + threadIdx.x;
  int v = (i < N) ? cnt[i] : 0;
  s[threadIdx.x] = v; __syncthreads();
  for (int off = 1; off < 256; off <<= 1){
    int x = 0;
    if (threadIdx.x >= off) x = s[threadIdx.x - off];
    __syncthreads();
    s[threadIdx.x] += x;
    __syncthreads();
  }
  if (i < N) rowptr[i + 1] = s[threadIdx.x];
  if (threadIdx.x == 255) bsums[blockIdx.x] = s[255];
}
__global__ void k_scan2(int* __restrict__ bsums, int nb){
  __shared__ int s[256];
  int t = threadIdx.x;
  int v = (t < nb) ? bsums[t] : 0;
  s[t] = v; __syncthreads();
  for (int off = 1; off < 256; off <<= 1){
    int x = 0;
    if (t >= off) x = s[t - off];
    __syncthreads();
    s[t] += x;
    __syncthreads();
  }
  if (t < nb) bsums[t] = s[t] - v;                // exclusive
}
__global__ void k_scan3(int* __restrict__ rowptr, const int* __restrict__ bsums,
                        int* __restrict__ cursor, int N){
  int i = blockIdx.x * 256 + threadIdx.x;
  if (i < N){
    int v = rowptr[i + 1] + bsums[blockIdx.x];
    rowptr[i + 1] = v;
    if (i + 1 < N) cursor[i + 1] = v;
    if (i == 0){ rowptr[0] = 0; cursor[0] = 0; }
  }
}
__global__ void k_scatter(const int* __restrict__ src, const int* __restrict__ dst,
                          int* __restrict__ cursor, int* __restrict__ csr_src, int E){
  int i = blockIdx.x * 256 + threadIdx.x;
  if (i < E){
    int p = atomicAdd(&cursor[dst[i]], 1);
    csr_src[p] = src[i];
  }
}

// ---------------- MFMA node GEMM (plain, for residual) ----------------
__global__ __launch_bounds__(256) void mfma_gemm(
    const u16* __restrict__ X, const u16* __restrict__ WT,
    u16* __restrict__ OUT, int N, int K)
{
  const int wave = threadIdx.x >> 6;
  const int lane = threadIdx.x & 63;
  const int m = lane & 15;
  const int q = lane >> 4;
  const int row0 = blockIdx.x * 64 + wave * 16;
  f32x4 acc[16];
  #pragma unroll
  for (int t = 0; t < 16; ++t) acc[t] = (f32x4){0.f, 0.f, 0.f, 0.f};
  const int arow = row0 + m;
  const bool rvalid = arow < N;
  const u16* aptr = X + (size_t)arow * K + q * 8;
  for (int k0 = 0; k0 < K; k0 += 32){
    bf16x8 a = {};
    if (rvalid) a = *(const bf16x8*)(aptr + k0);
    #pragma unroll
    for (int t = 0; t < 16; ++t){
      const u16* bptr = WT + (size_t)(t * 16 + m) * K + k0 + q * 8;
      bf16x8 b = *(const bf16x8*)bptr;
      acc[t] = __builtin_amdgcn_mfma_f32_16x16x32_bf16(a, b, acc[t], 0, 0, 0);
    }
  }
  #pragma unroll
  for (int t = 0; t < 16; ++t){
    int col = t * 16 + m;
    #pragma unroll
    for (int r = 0; r < 4; ++r){
      int rr = row0 + q * 4 + r;
      if (rr < N) OUT[(size_t)rr * 256 + col] = f2bf(acc[t][r]);
    }
  }
}

// ---------------- MFMA node GEMM + fused attention logits ----------------
// Writes FT bf16 and el4/er4 (float4 per node) from the fp32 accumulators.
__global__ __launch_bounds__(256) void mfma_gemm_attn(
    const u16* __restrict__ X, const u16* __restrict__ WT,
    u16* __restrict__ OUT, const u16* __restrict__ al, const u16* __restrict__ ar,
    float* __restrict__ el4, float* __restrict__ er4, int N, int K)
{
  const int wave = threadIdx.x >> 6;
  const int lane = threadIdx.x & 63;
  const int m = lane & 15;
  const int q = lane >> 4;
  const int row0 = blockIdx.x * 64 + wave * 16;
  float alv[16], arv[16];
  #pragma unroll
  for (int t = 0; t < 16; ++t){
    alv[t] = bf2f(al[t * 16 + m]);
    arv[t] = bf2f(ar[t * 16 + m]);
  }
  f32x4 acc[16];
  #pragma unroll
  for (int t = 0; t < 16; ++t) acc[t] = (f32x4){0.f, 0.f, 0.f, 0.f};
  const int arow = row0 + m;
  const bool rvalid = arow < N;
  const u16* aptr = X + (size_t)arow * K + q * 8;
  for (int k0 = 0; k0 < K; k0 += 32){
    bf16x8 a = {};
    if (rvalid) a = *(const bf16x8*)(aptr + k0);
    #pragma unroll
    for (int t = 0; t < 16; ++t){
      const u16* bptr = WT + (size_t)(t * 16 + m) * K + k0 + q * 8;
      bf16x8 b = *(const bf16x8*)bptr;
      acc[t] = __builtin_amdgcn_mfma_f32_16x16x32_bf16(a, b, acc[t], 0, 0, 0);
    }
  }
  // fused el/er epilogue: el[n,h] = sum_{c in head h} ft[n,c]*al[c]
  #pragma unroll
  for (int r = 0; r < 4; ++r){
    float pe[4] = {0.f, 0.f, 0.f, 0.f}, pr[4] = {0.f, 0.f, 0.f, 0.f};
    #pragma unroll
    for (int t = 0; t < 16; ++t){
      pe[t >> 2] += acc[t][r] * alv[t];
      pr[t >> 2] += acc[t][r] * arv[t];
    }
    #pragma unroll
    for (int mk = 1; mk < 16; mk <<= 1){
      #pragma unroll
      for (int hh = 0; hh < 4; ++hh){
        pe[hh] += __shfl_xor(pe[hh], mk);
        pr[hh] += __shfl_xor(pr[hh], mk);
      }
    }
    int rr = row0 + q * 4 + r;
    if (m == 0 && rr < N){
      *(f32x4*)(el4 + (size_t)rr * 4) = (f32x4){pe[0], pe[1], pe[2], pe[3]};
      *(f32x4*)(er4 + (size_t)rr * 4) = (f32x4){pr[0], pr[1], pr[2], pr[3]};
    }
  }
  #pragma unroll
  for (int t = 0; t < 16; ++t){
    int col = t * 16 + m;
    #pragma unroll
    for (int r = 0; r < 4; ++r){
      int rr = row0 + q * 4 + r;
      if (rr < N) OUT[(size_t)rr * 256 + col] = f2bf(acc[t][r]);
    }
  }
}

// ---------------- aggregation v3: 1 wave = 1 dst, logits fused, no barriers ---
__global__ __launch_bounds__(256) void aggregate3(
    const u16* __restrict__ ft, const float* __restrict__ el4, const float* __restrict__ er4,
    const int* __restrict__ rowptr, const int* __restrict__ csr_src,
    const u16* __restrict__ residb, u16* __restrict__ outb,
    u16* __restrict__ hf, int do_hf, int N)
{
  __shared__ float sal[4][64][4];     // wave-private alpha [wave][edge][head]
  __shared__ int   sof[4][64];        // wave-private row byte offsets
  const int w = threadIdx.x >> 6, lane = threadIdx.x & 63;
  const int d = blockIdx.x * 4 + w;
  if (d >= N) return;
  const int beg = rowptr[d], deg = rowptr[d + 1] - beg;
  const int hg = lane >> 4;           // this lane's head (cols lane*4..lane*4+3)
  float a0 = 0.f, a1 = 0.f, a2 = 0.f, a3 = 0.f;

  if (deg > 0){
    const float4 erd = ((const float4*)er4)[d];
    const int dc = min(deg, 64);
    float m0 = -3.0e38f, m1 = -3.0e38f, m2 = -3.0e38f, m3 = -3.0e38f;
    float ec0 = 0.f, ec1 = 0.f, ec2 = 0.f, ec3 = 0.f; int sc = 0;
    for (int j = lane; j < deg; j += 64){
      int s = csr_src[beg + j];
      float4 ql = ((const float4*)el4)[s];
      float e0 = ql.x + erd.x; e0 = (e0 > 0.f) ? e0 : 0.2f * e0;
      float e1 = ql.y + erd.y; e1 = (e1 > 0.f) ? e1 : 0.2f * e1;
      float e2 = ql.z + erd.z; e2 = (e2 > 0.f) ? e2 : 0.2f * e2;
      float e3 = ql.w + erd.w; e3 = (e3 > 0.f) ? e3 : 0.2f * e3;
      if (j < 64){ ec0 = e0; ec1 = e1; ec2 = e2; ec3 = e3; sc = s; }
      m0 = fmaxf(m0, e0); m1 = fmaxf(m1, e1);
      m2 = fmaxf(m2, e2); m3 = fmaxf(m3, e3);
    }
    for (int mk = 1; mk < dc; mk <<= 1){
      m0 = fmaxf(m0, __shfl_xor(m0, mk)); m1 = fmaxf(m1, __shfl_xor(m1, mk));
      m2 = fmaxf(m2, __shfl_xor(m2, mk)); m3 = fmaxf(m3, __shfl_xor(m3, mk));
    }
    float x0 = 0.f, x1 = 0.f, x2 = 0.f, x3 = 0.f;       // chunk-0 exp cache
    float d0 = 0.f, d1 = 0.f, d2 = 0.f, d3 = 0.f;
    for (int j = lane; j < deg; j += 64){
      float e0, e1, e2, e3;
      if (j < 64){ e0 = ec0; e1 = ec1; e2 = ec2; e3 = ec3; }
      else {
        int s = csr_src[beg + j];
        float4 ql = ((const float4*)el4)[s];
        e0 = ql.x + erd.x; e0 = (e0 > 0.f) ? e0 : 0.2f * e0;
        e1 = ql.y + erd.y; e1 = (e1 > 0.f) ? e1 : 0.2f * e1;
        e2 = ql.z + erd.z; e2 = (e2 > 0.f) ? e2 : 0.2f * e2;
        e3 = ql.w + erd.w; e3 = (e3 > 0.f) ? e3 : 0.2f * e3;
      }
      float t0 = __expf(e0 - m0), t1 = __expf(e1 - m1);
      float t2 = __expf(e2 - m2), t3 = __expf(e3 - m3);
      if (j < 64){ x0 = t0; x1 = t1; x2 = t2; x3 = t3; }
      d0 += t0; d1 += t1; d2 += t2; d3 += t3;
    }
    for (int mk = 1; mk < dc; mk <<= 1){
      d0 += __shfl_xor(d0, mk); d1 += __shfl_xor(d1, mk);
      d2 += __shfl_xor(d2, mk); d3 += __shfl_xor(d3, mk);
    }
    const float i0 = 1.f / d0, i1 = 1.f / d1, i2 = 1.f / d2, i3 = 1.f / d3;

    for (int c0 = 0; c0 < deg; c0 += 64){
      int cs = min(64, deg - c0);
      if (lane < cs){
        float t0, t1, t2, t3; int s;
        if (c0 == 0){ t0 = x0; t1 = x1; t2 = x2; t3 = x3; s = sc; }
        else {
          s = csr_src[beg + c0 + lane];
          float4 ql = ((const float4*)el4)[s];
          float e0 = ql.x + erd.x; e0 = (e0 > 0.f) ? e0 : 0.2f * e0;
          float e1 = ql.y + erd.y; e1 = (e1 > 0.f) ? e1 : 0.2f * e1;
          float e2 = ql.z + erd.z; e2 = (e2 > 0.f) ? e2 : 0.2f * e2;
          float e3 = ql.w + erd.w; e3 = (e3 > 0.f) ? e3 : 0.2f * e3;
          t0 = __expf(e0 - m0); t1 = __expf(e1 - m1);
          t2 = __expf(e2 - m2); t3 = __expf(e3 - m3);
        }
        sal[w][lane][0] = t0 * i0; sal[w][lane][1] = t1 * i1;
        sal[w][lane][2] = t2 * i2; sal[w][lane][3] = t3 * i3;
        sof[w][lane] = s << 9;                      // s * 512 bytes
      }
      __builtin_amdgcn_wave_barrier();
      for (int j = 0; j < cs; ++j){
        float av = sal[w][j][hg];
        int off = sof[w][j];
        uint2 v = *(const uint2*)((const char*)ft + (size_t)off + lane * 8);
        union { unsigned u; float f; } c0_, c1_, c2_, c3_;
        c0_.u = v.x << 16; c1_.u = v.x & 0xffff0000u;
        c2_.u = v.y << 16; c3_.u = v.y & 0xffff0000u;
        a0 += av * c0_.f; a1 += av * c1_.f;
        a2 += av * c2_.f; a3 += av * c3_.f;
      }
      __builtin_amdgcn_wave_barrier();
    }
  }
  // residual + output
  const int col0 = lane * 4;
  uint2 rv = *(const uint2*)(residb + (size_t)d * 256 + col0);
  union { unsigned u; float f; } r0, r1, r2, r3;
  r0.u = rv.x << 16; r1.u = rv.x & 0xffff0000u;
  r2.u = rv.y << 16; r3.u = rv.y & 0xffff0000u;
  float o0 = a0 + r0.f, o1 = a1 + r1.f, o2 = a2 + r2.f, o3 = a3 + r3.f;
  if (!do_hf){
    o0 = fmaxf(o0, 0.f); o1 = fmaxf(o1, 0.f);
    o2 = fmaxf(o2, 0.f); o3 = fmaxf(o3, 0.f);
    uint2 ov;
    ov.x = (unsigned)f2bf(o0) | ((unsigned)f2bf(o1) << 16);
    ov.y = (unsigned)f2bf(o2) | ((unsigned)f2bf(o3) << 16);
    *(uint2*)(outb + (size_t)d * 256 + col0) = ov;
  } else {
    // head-mean: sum over lane bits 4,5 (the head bits)
    o0 += __shfl_xor(o0, 16); o0 += __shfl_xor(o0, 32);
    o1 += __shfl_xor(o1, 16); o1 += __shfl_xor(o1, 32);
    o2 += __shfl_xor(o2, 16); o2 += __shfl_xor(o2, 32);
    o3 += __shfl_xor(o3, 16); o3 += __shfl_xor(o3, 32);
    if (lane < 16){
      uint2 ov;
      ov.x = (unsigned)f2bf(0.25f * o0) | ((unsigned)f2bf(0.25f * o1) << 16);
      ov.y = (unsigned)f2bf(0.25f * o2) | ((unsigned)f2bf(0.25f * o3) << 16);
      *(uint2*)(hf + (size_t)d * 64 + lane * 4) = ov;
    }
  }
}

// ---------------- MFMA edge MLP: 1 wave = 16 edges/tile -----------------------
__global__ __launch_bounds__(256) void edge_mlp_mfma(
    const u16* __restrict__ hfb,
    const int* __restrict__ src, const int* __restrict__ dst,
    const u16* __restrict__ Wm1, const u16* __restrict__ bm1,
    const u16* __restrict__ Wm2, const u16* __restrict__ bm2,
    void* __restrict__ out, int E, const int* __restrict__ flag)
{
  const int lane = threadIdx.x & 63;
  const int m = lane & 15;
  const int q = lane >> 4;
  const int is_f32 = *flag;

  bf16x8 bfr[4][2];
  #pragma unroll
  for (int t = 0; t < 4; ++t)
    #pragma unroll
    for (int ks = 0; ks < 2; ++ks)
      #pragma unroll
      for (int j = 0; j < 8; ++j)
        bfr[t][ks][j] = (short)Wm1[(size_t)(ks * 32 + q * 8 + j) * 64 + t * 16 + m];

  float b1v[4], w2v[4];
  #pragma unroll
  for (int t = 0; t < 4; ++t){
    b1v[t] = bf2f(bm1[t * 16 + m]);
    w2v[t] = bf2f(Wm2[t * 16 + m]);
  }
  const float b2 = bf2f(bm2[0]);

  const int wid = blockIdx.x * 4 + (threadIdx.x >> 6);
  const int nw  = gridDim.x * 4;
  for (int e0 = wid * 16; e0 < E; e0 += nw * 16){
    int e = e0 + m; if (e >= E) e = E - 1;
    const int s = src[e], d = dst[e];
    const u16* ps = hfb + (size_t)s * 64;
    const u16* pd = hfb + (size_t)d * 64;
    bf16x8 af[2];
    #pragma unroll
    for (int ks = 0; ks < 2; ++ks){
      bf16x8 vs = *(const bf16x8*)(ps + ks * 32 + q * 8);
      bf16x8 vd = *(const bf16x8*)(pd + ks * 32 + q * 8);
      #pragma unroll
      for (int j = 0; j < 8; ++j)
        af[ks][j] = (short)f2bf(fabsf(bf2f((u16)vs[j]) - bf2f((u16)vd[j])));
    }
    f32x4 acc[4];
    #pragma unroll
    for (int t = 0; t < 4; ++t) acc[t] = (f32x4){0.f, 0.f, 0.f, 0.f};
    #pragma unroll
    for (int ks = 0; ks < 2; ++ks)
      #pragma unroll
      for (int t = 0; t < 4; ++t)
        acc[t] = __builtin_amdgcn_mfma_f32_16x16x32_bf16(af[ks], bfr[t][ks], acc[t], 0, 0, 0);
    #pragma unroll
    for (int r = 0; r < 4; ++r){
      float p = 0.f;
      #pragma unroll
      for (int t = 0; t < 4; ++t)
        p += fmaxf(acc[t][r] + b1v[t], 0.f) * w2v[t];
      #pragma unroll
      for (int mm = 1; mm < 16; mm <<= 1) p += __shfl_xor(p, mm);
      int er = e0 + q * 4 + r;
      if (m == 0 && er < E){
        float sc = 1.f / (1.f + __expf(-(p + b2)));
        if (is_f32) ((float*)out)[er] = sc;
        else        ((u16*)out)[er]   = f2bf(sc);
      }
    }
  }
}

extern "C" void kernel_launch(void* const* d_in, const int* in_sizes, int n_in,
                              void* d_out, int out_size, void* d_ws, size_t ws_size,
                              hipStream_t stream)
{
  const int* src = (const int*)d_in[1];
  const int* dst = (const int*)d_in[2];

  const int N = in_sizes[0] / 128;
  const int E = in_sizes[1];

  char* p = (char*)d_ws;
  auto alloc = [&](size_t bytes) -> char* {
    char* r = p; p += (bytes + 255) & ~(size_t)255; return r;
  };
  int* flag   = (int*)  alloc(4);
  u16* hc     = (u16*)  alloc((size_t)N * 128 * 2);
  u16* FT     = (u16*)  alloc((size_t)N * 256 * 2);
  u16* XA     = (u16*)  alloc((size_t)N * 256 * 2);
  u16* XB     = (u16*)  alloc((size_t)N * 256 * 2);
  float* el   = (float*)alloc((size_t)N * 4 * 4);
  float* er   = (float*)alloc((size_t)N * 4 * 4);
  u16* hfb    = (u16*)  alloc((size_t)N * 64 * 2);
  int* rowptr = (int*)  alloc((size_t)(N + 1) * 4);
  int* cursor = (int*)  alloc((size_t)N * 4);
  int* csr    = (int*)  alloc((size_t)E * 4);
  int* bsums  = (int*)  alloc(1024);
  u16* WT1    = (u16*)  alloc(128 * 256 * 2);
  u16* WTr1   = (u16*)  alloc(128 * 256 * 2);
  u16* WT2    = (u16*)  alloc(256 * 256 * 2);
  u16* WT3    = (u16*)  alloc(256 * 256 * 2);
  u16* al1c   = (u16*)  alloc(256 * 2);
  u16* ar1c   = (u16*)  alloc(256 * 2);
  u16* al2c   = (u16*)  alloc(256 * 2);
  u16* ar2c   = (u16*)  alloc(256 * 2);
  u16* al3c   = (u16*)  alloc(256 * 2);
  u16* ar3c   = (u16*)  alloc(256 * 2);
  u16* Wm1c   = (u16*)  alloc(4096 * 2);
  u16* bm1c   = (u16*)  alloc(64 * 2);
  u16* Wm2c   = (u16*)  alloc(64 * 2);
  u16* bm2c   = (u16*)  alloc(2);

  const int nb = (N + 255) / 256;
  const int ge = (E + 255) / 256;

  // dtype sniff + canonicalize
  k_sniff<<<1, 256, 0, stream>>>((const u16*)d_in[0], flag);
  k_canon<<<(N * 128 + 255) / 256, 256, 0, stream>>>(d_in[0], hc, N * 128, flag);
  {
    Canon10 c;
    c.e[0] = {d_in[5],  al1c, 256};  c.e[1] = {d_in[6],  ar1c, 256};
    c.e[2] = {d_in[8],  al2c, 256};  c.e[3] = {d_in[9],  ar2c, 256};
    c.e[4] = {d_in[11], al3c, 256};  c.e[5] = {d_in[12], ar3c, 256};
    c.e[6] = {d_in[13], Wm1c, 4096}; c.e[7] = {d_in[14], bm1c, 64};
    c.e[8] = {d_in[15], Wm2c, 64};   c.e[9] = {d_in[16], bm2c, 1};
    dim3 g((4096 + 255) / 256, 10);
    k_canon10<<<g, 256, 0, stream>>>(c, flag);
  }
  {
    CanonW4 c;
    c.e[0] = {d_in[3],  WT1,  128};  c.e[1] = {d_in[4],  WTr1, 128};
    c.e[2] = {d_in[7],  WT2,  256};  c.e[3] = {d_in[10], WT3,  256};
    dim3 g(256, 4);
    k_canonw<<<g, 256, 0, stream>>>(c, flag);
  }

  // CSR by dst
  k_zero<<<nb, 256, 0, stream>>>(cursor, N);
  k_hist<<<ge, 256, 0, stream>>>(dst, cursor, E);
  k_scan1<<<nb, 256, 0, stream>>>(cursor, rowptr, bsums, N);
  k_scan2<<<1, 256, 0, stream>>>(bsums, nb);
  k_scan3<<<nb, 256, 0, stream>>>(rowptr, bsums, cursor, N);
  k_scatter<<<ge, 256, 0, stream>>>(src, dst, cursor, csr, E);

  const int gA = (N + 63) / 64;
  const int gG = (N + 3) / 4;
  // layer 1
  mfma_gemm_attn<<<gA, 256, 0, stream>>>(hc, WT1, FT, al1c, ar1c, el, er, N, 128);
  mfma_gemm<<<gA, 256, 0, stream>>>(hc, WTr1, XA, N, 128);
  aggregate3<<<gG, 256, 0, stream>>>(FT, el, er, rowptr, csr, XA, XB, nullptr, 0, N);
  // layer 2
  mfma_gemm_attn<<<gA, 256, 0, stream>>>(XB, WT2, FT, al2c, ar2c, el, er, N, 256);
  aggregate3<<<gG, 256, 0, stream>>>(FT, el, er, rowptr, csr, XB, XA, nullptr, 0, N);
  // layer 3 (fused head-mean -> hf bf16)
  mfma_gemm_attn<<<gA, 256, 0, stream>>>(XA, WT3, FT, al3c, ar3c, el, er, N, 256);
  aggregate3<<<gG, 256, 0, stream>>>(FT, el, er, rowptr, csr, XA, nullptr, hfb, 1, N);
  // edge MLP (MFMA)
  edge_mlp_mfma<<<2048, 256, 0, stream>>>(hfb, src, dst, Wm1c, bm1c, Wm2c, bm2c,
                                          d_out, E, flag);
}

// Round 6
// 654.982 us; speedup vs baseline: 4.0569x; 1.0732x over previous
//
#include <hip/hip_runtime.h>

typedef unsigned short u16;
typedef __attribute__((ext_vector_type(8))) short bf16x8;
typedef __attribute__((ext_vector_type(4))) float f32x4;

__device__ __forceinline__ float bf2f(u16 u){
  union { unsigned int i; float f; } v; v.i = ((unsigned int)u) << 16; return v.f;
}
__device__ __forceinline__ u16 f2bf(float f){
  union { float f; unsigned int i; } v; v.f = f;
  unsigned int lsb = (v.i >> 16) & 1u;
  v.i += 0x7fffu + lsb;
  return (u16)(v.i >> 16);
}
__device__ __forceinline__ void fma2(float& a0, float& a1, unsigned p, float s){
  union { unsigned u; float f; } lo, hi;
  lo.u = p << 16; hi.u = p & 0xffff0000u;
  a0 += s * lo.f; a1 += s * hi.f;
}

// ---------------- dtype sniffer ----------------
__global__ void k_sniff(const u16* __restrict__ p, int* __restrict__ flag){
  __shared__ int s[256];
  int tid = threadIdx.x;
  u16 v = p[2 * tid];
  int e = (v >> 7) & 0xFF;
  s[tid] = (e >= 100 && e <= 135) ? 1 : 0;
  __syncthreads();
  for (int off = 128; off; off >>= 1){
    if (tid < off) s[tid] += s[tid + off];
    __syncthreads();
  }
  if (tid == 0) *flag = (s[0] < 180) ? 1 : 0;
}
__global__ void k_canon(const void* __restrict__ src, u16* __restrict__ dst,
                        int n, const int* __restrict__ flag){
  int i = blockIdx.x * 256 + threadIdx.x;
  if (i < n){
    if (*flag) dst[i] = f2bf(((const float*)src)[i]);
    else       dst[i] = ((const u16*)src)[i];
  }
}
struct CanonEnt { const void* s; u16* d; int n; };
struct Canon10 { CanonEnt e[10]; };
__global__ void k_canon10(Canon10 c, const int* __restrict__ flag){
  CanonEnt en = c.e[blockIdx.y];
  int i = blockIdx.x * 256 + threadIdx.x;
  if (i < en.n){
    if (*flag) en.d[i] = f2bf(((const float*)en.s)[i]);
    else       en.d[i] = ((const u16*)en.s)[i];
  }
}
struct CanonWEnt { const void* s; u16* wt; int K; };
struct CanonW4 { CanonWEnt e[4]; };
__global__ void k_canonw(CanonW4 c, const int* __restrict__ flag){
  CanonWEnt en = c.e[blockIdx.y];
  int i = blockIdx.x * 256 + threadIdx.x;
  if (i < 256 * en.K){
    int k = i >> 8, cc = i & 255;
    u16 b;
    if (*flag) b = f2bf(((const float*)en.s)[i]);
    else       b = ((const u16*)en.s)[i];
    en.wt[(size_t)cc * en.K + k] = b;
  }
}

// ---------------- CSR build ----------------
__global__ void k_zero(int* __restrict__ p, int n){
  int i = blockIdx.x * 256 + threadIdx.x;
  if (i < n) p[i] = 0;
}
__global__ void k_hist(const int* __restrict__ dst, int* __restrict__ cnt, int E){
  int i = blockIdx.x * 256 + threadIdx.x;
  if (i < E) atomicAdd(&cnt[dst[i]], 1);
}
__global__ void k_scan1(const int* __restrict__ cnt, int* __restrict__ rowptr,
                        int* __restrict__ bsums, int N){
  __shared__ int s[256];
  int i = blockIdx.x * 256 + threadIdx.x;
  int v = (i < N) ? cnt[i] : 0;
  s[threadIdx.x] = v; __syncthreads();
  for (int off = 1; off < 256; off <<= 1){
    int x = 0;
    if (threadIdx.x >= off) x = s[threadIdx.x - off];
    __syncthreads();
    s[threadIdx.x] += x;
    __syncthreads();
  }
  if (i < N) rowptr[i + 1] = s[threadIdx.x];
  if (threadIdx.x == 255) bsums[blockIdx.x] = s[255];
}
__global__ void k_scan2(int* __restrict__ bsums, int nb){
  __shared__ int s[256];
  int t = threadIdx.x;
  int v = (t < nb) ? bsums[t] : 0;
  s[t] = v; __syncthreads();
  for (int off = 1; off < 256; off <<= 1){
    int x = 0;
    if (t >= off) x = s[t - off];
    __syncthreads();
    s[t] += x;
    __syncthreads();
  }
  if (t < nb) bsums[t] = s[t] - v;                // exclusive
}
__global__ void k_scan3(int* __restrict__ rowptr, const int* __restrict__ bsums,
                        int* __restrict__ cursor, int N){
  int i = blockIdx.x * 256 + threadIdx.x;
  if (i < N){
    int v = rowptr[i + 1] + bsums[blockIdx.x];
    rowptr[i + 1] = v;
    if (i + 1 < N) cursor[i + 1] = v;
    if (i == 0){ rowptr[0] = 0; cursor[0] = 0; }
  }
}
__global__ void k_scatter(const int* __restrict__ src, const int* __restrict__ dst,
                          int* __restrict__ cursor, int* __restrict__ csr_src, int E){
  int i = blockIdx.x * 256 + threadIdx.x;
  if (i < E){
    int p = atomicAdd(&cursor[dst[i]], 1);
    csr_src[p] = src[i];
  }
}

// ---------------- MFMA node GEMM v2: 32 rows/wave, 128 rows/block -------------
__global__ __launch_bounds__(256) void mfma_gemm2(
    const u16* __restrict__ X, const u16* __restrict__ WT,
    u16* __restrict__ OUT, int N, int K)
{
  const int wave = threadIdx.x >> 6;
  const int lane = threadIdx.x & 63;
  const int m = lane & 15;
  const int q = lane >> 4;
  const int row0 = blockIdx.x * 128 + wave * 32;
  f32x4 acc[2][16];
  #pragma unroll
  for (int g = 0; g < 2; ++g)
    #pragma unroll
    for (int t = 0; t < 16; ++t) acc[g][t] = (f32x4){0.f, 0.f, 0.f, 0.f};
  const int rA = row0 + m, rB = row0 + 16 + m;
  const bool vA = rA < N, vB = rB < N;
  const u16* apA = X + (size_t)rA * K + q * 8;
  const u16* apB = X + (size_t)rB * K + q * 8;
  for (int k0 = 0; k0 < K; k0 += 32){
    bf16x8 aA = {}, aB = {};
    if (vA) aA = *(const bf16x8*)(apA + k0);
    if (vB) aB = *(const bf16x8*)(apB + k0);
    #pragma unroll
    for (int t = 0; t < 16; ++t){
      const u16* bptr = WT + (size_t)(t * 16 + m) * K + k0 + q * 8;
      bf16x8 b = *(const bf16x8*)bptr;
      acc[0][t] = __builtin_amdgcn_mfma_f32_16x16x32_bf16(aA, b, acc[0][t], 0, 0, 0);
      acc[1][t] = __builtin_amdgcn_mfma_f32_16x16x32_bf16(aB, b, acc[1][t], 0, 0, 0);
    }
  }
  #pragma unroll
  for (int g = 0; g < 2; ++g)
    #pragma unroll
    for (int t = 0; t < 16; ++t){
      int col = t * 16 + m;
      #pragma unroll
      for (int r = 0; r < 4; ++r){
        int rr = row0 + g * 16 + q * 4 + r;
        if (rr < N) OUT[(size_t)rr * 256 + col] = f2bf(acc[g][t][r]);
      }
    }
}

// ---------------- MFMA node GEMM v2 + fused attention logits ------------------
__global__ __launch_bounds__(256) void mfma_gemm_attn2(
    const u16* __restrict__ X, const u16* __restrict__ WT,
    u16* __restrict__ OUT, const u16* __restrict__ al, const u16* __restrict__ ar,
    float* __restrict__ el4, float* __restrict__ er4, int N, int K)
{
  const int wave = threadIdx.x >> 6;
  const int lane = threadIdx.x & 63;
  const int m = lane & 15;
  const int q = lane >> 4;
  const int row0 = blockIdx.x * 128 + wave * 32;
  float alv[16], arv[16];
  #pragma unroll
  for (int t = 0; t < 16; ++t){
    alv[t] = bf2f(al[t * 16 + m]);
    arv[t] = bf2f(ar[t * 16 + m]);
  }
  f32x4 acc[2][16];
  #pragma unroll
  for (int g = 0; g < 2; ++g)
    #pragma unroll
    for (int t = 0; t < 16; ++t) acc[g][t] = (f32x4){0.f, 0.f, 0.f, 0.f};
  const int rA = row0 + m, rB = row0 + 16 + m;
  const bool vA = rA < N, vB = rB < N;
  const u16* apA = X + (size_t)rA * K + q * 8;
  const u16* apB = X + (size_t)rB * K + q * 8;
  for (int k0 = 0; k0 < K; k0 += 32){
    bf16x8 aA = {}, aB = {};
    if (vA) aA = *(const bf16x8*)(apA + k0);
    if (vB) aB = *(const bf16x8*)(apB + k0);
    #pragma unroll
    for (int t = 0; t < 16; ++t){
      const u16* bptr = WT + (size_t)(t * 16 + m) * K + k0 + q * 8;
      bf16x8 b = *(const bf16x8*)bptr;
      acc[0][t] = __builtin_amdgcn_mfma_f32_16x16x32_bf16(aA, b, acc[0][t], 0, 0, 0);
      acc[1][t] = __builtin_amdgcn_mfma_f32_16x16x32_bf16(aB, b, acc[1][t], 0, 0, 0);
    }
  }
  // fused el/er epilogue
  #pragma unroll
  for (int g = 0; g < 2; ++g)
    #pragma unroll
    for (int r = 0; r < 4; ++r){
      float pe[4] = {0.f, 0.f, 0.f, 0.f}, pr[4] = {0.f, 0.f, 0.f, 0.f};
      #pragma unroll
      for (int t = 0; t < 16; ++t){
        pe[t >> 2] += acc[g][t][r] * alv[t];
        pr[t >> 2] += acc[g][t][r] * arv[t];
      }
      #pragma unroll
      for (int mk = 1; mk < 16; mk <<= 1){
        #pragma unroll
        for (int hh = 0; hh < 4; ++hh){
          pe[hh] += __shfl_xor(pe[hh], mk);
          pr[hh] += __shfl_xor(pr[hh], mk);
        }
      }
      int rr = row0 + g * 16 + q * 4 + r;
      if (m == 0 && rr < N){
        *(f32x4*)(el4 + (size_t)rr * 4) = (f32x4){pe[0], pe[1], pe[2], pe[3]};
        *(f32x4*)(er4 + (size_t)rr * 4) = (f32x4){pr[0], pr[1], pr[2], pr[3]};
      }
    }
  #pragma unroll
  for (int g = 0; g < 2; ++g)
    #pragma unroll
    for (int t = 0; t < 16; ++t){
      int col = t * 16 + m;
      #pragma unroll
      for (int r = 0; r < 4; ++r){
        int rr = row0 + g * 16 + q * 4 + r;
        if (rr < N) OUT[(size_t)rr * 256 + col] = f2bf(acc[g][t][r]);
      }
    }
}

// ---------------- aggregation v4: 1 wave = 1 dst, 16B/lane, 2 edges/iter ------
__global__ __launch_bounds__(256) void aggregate4(
    const u16* __restrict__ ft, const float* __restrict__ el4, const float* __restrict__ er4,
    const int* __restrict__ rowptr, const int* __restrict__ csr_src,
    const u16* __restrict__ residb, u16* __restrict__ outb,
    u16* __restrict__ hf, int do_hf, int N)
{
  __shared__ float sal[4][64][4];
  __shared__ int   sof[4][64];
  const int w = threadIdx.x >> 6, lane = threadIdx.x & 63;
  const int d = blockIdx.x * 4 + w;
  if (d >= N) return;
  const int beg = rowptr[d], deg = rowptr[d + 1] - beg;
  const int H = lane >> 5;            // edge-parity half
  const int c = lane & 31;            // col group: cols c*8 .. c*8+7
  const int hg = c >> 3;              // head of those cols
  float acc[8] = {0.f, 0.f, 0.f, 0.f, 0.f, 0.f, 0.f, 0.f};

  if (deg > 0){
    const float4 erd = ((const float4*)er4)[d];
    const int dc = min(deg, 64);
    float m0 = -3.0e38f, m1 = -3.0e38f, m2 = -3.0e38f, m3 = -3.0e38f;
    float ec0 = 0.f, ec1 = 0.f, ec2 = 0.f, ec3 = 0.f; int sc = 0;
    for (int j = lane; j < deg; j += 64){
      int s = csr_src[beg + j];
      float4 ql = ((const float4*)el4)[s];
      float e0 = ql.x + erd.x; e0 = (e0 > 0.f) ? e0 : 0.2f * e0;
      float e1 = ql.y + erd.y; e1 = (e1 > 0.f) ? e1 : 0.2f * e1;
      float e2 = ql.z + erd.z; e2 = (e2 > 0.f) ? e2 : 0.2f * e2;
      float e3 = ql.w + erd.w; e3 = (e3 > 0.f) ? e3 : 0.2f * e3;
      if (j < 64){ ec0 = e0; ec1 = e1; ec2 = e2; ec3 = e3; sc = s; }
      m0 = fmaxf(m0, e0); m1 = fmaxf(m1, e1);
      m2 = fmaxf(m2, e2); m3 = fmaxf(m3, e3);
    }
    for (int mk = 1; mk < dc; mk <<= 1){
      m0 = fmaxf(m0, __shfl_xor(m0, mk)); m1 = fmaxf(m1, __shfl_xor(m1, mk));
      m2 = fmaxf(m2, __shfl_xor(m2, mk)); m3 = fmaxf(m3, __shfl_xor(m3, mk));
    }
    float x0 = 0.f, x1 = 0.f, x2 = 0.f, x3 = 0.f;
    float d0 = 0.f, d1 = 0.f, d2 = 0.f, d3 = 0.f;
    for (int j = lane; j < deg; j += 64){
      float e0, e1, e2, e3;
      if (j < 64){ e0 = ec0; e1 = ec1; e2 = ec2; e3 = ec3; }
      else {
        int s = csr_src[beg + j];
        float4 ql = ((const float4*)el4)[s];
        e0 = ql.x + erd.x; e0 = (e0 > 0.f) ? e0 : 0.2f * e0;
        e1 = ql.y + erd.y; e1 = (e1 > 0.f) ? e1 : 0.2f * e1;
        e2 = ql.z + erd.z; e2 = (e2 > 0.f) ? e2 : 0.2f * e2;
        e3 = ql.w + erd.w; e3 = (e3 > 0.f) ? e3 : 0.2f * e3;
      }
      float t0 = __expf(e0 - m0), t1 = __expf(e1 - m1);
      float t2 = __expf(e2 - m2), t3 = __expf(e3 - m3);
      if (j < 64){ x0 = t0; x1 = t1; x2 = t2; x3 = t3; }
      d0 += t0; d1 += t1; d2 += t2; d3 += t3;
    }
    for (int mk = 1; mk < dc; mk <<= 1){
      d0 += __shfl_xor(d0, mk); d1 += __shfl_xor(d1, mk);
      d2 += __shfl_xor(d2, mk); d3 += __shfl_xor(d3, mk);
    }
    const float i0 = 1.f / d0, i1 = 1.f / d1, i2 = 1.f / d2, i3 = 1.f / d3;

    for (int c0 = 0; c0 < deg; c0 += 64){
      int cs = min(64, deg - c0);
      if (lane < cs){
        float t0, t1, t2, t3; int s;
        if (c0 == 0){ t0 = x0; t1 = x1; t2 = x2; t3 = x3; s = sc; }
        else {
          s = csr_src[beg + c0 + lane];
          float4 ql = ((const float4*)el4)[s];
          float e0 = ql.x + erd.x; e0 = (e0 > 0.f) ? e0 : 0.2f * e0;
          float e1 = ql.y + erd.y; e1 = (e1 > 0.f) ? e1 : 0.2f * e1;
          float e2 = ql.z + erd.z; e2 = (e2 > 0.f) ? e2 : 0.2f * e2;
          float e3 = ql.w + erd.w; e3 = (e3 > 0.f) ? e3 : 0.2f * e3;
          t0 = __expf(e0 - m0); t1 = __expf(e1 - m1);
          t2 = __expf(e2 - m2); t3 = __expf(e3 - m3);
        }
        sal[w][lane][0] = t0 * i0; sal[w][lane][1] = t1 * i1;
        sal[w][lane][2] = t2 * i2; sal[w][lane][3] = t3 * i3;
        sof[w][lane] = s << 9;                      // s * 512 bytes
      }
      __builtin_amdgcn_wave_barrier();
      for (int j0 = 0; j0 < cs; j0 += 2){
        int jA = j0 + H;
        if (jA < cs){
          float av = sal[w][jA][hg];
          int off = sof[w][jA];
          uint4 v = *(const uint4*)((const char*)ft + (size_t)(unsigned)off + c * 16);
          fma2(acc[0], acc[1], v.x, av);
          fma2(acc[2], acc[3], v.y, av);
          fma2(acc[4], acc[5], v.z, av);
          fma2(acc[6], acc[7], v.w, av);
        }
      }
      __builtin_amdgcn_wave_barrier();
    }
  }
  // combine the two edge-parity halves
  #pragma unroll
  for (int i = 0; i < 8; ++i) acc[i] += __shfl_xor(acc[i], 32);
  // residual (both halves load identically)
  uint4 rv = *(const uint4*)(residb + (size_t)d * 256 + c * 8);
  float rr[8];
  {
    union { unsigned u; float f; } t;
    t.u = rv.x << 16; rr[0] = t.f; t.u = rv.x & 0xffff0000u; rr[1] = t.f;
    t.u = rv.y << 16; rr[2] = t.f; t.u = rv.y & 0xffff0000u; rr[3] = t.f;
    t.u = rv.z << 16; rr[4] = t.f; t.u = rv.z & 0xffff0000u; rr[5] = t.f;
    t.u = rv.w << 16; rr[6] = t.f; t.u = rv.w & 0xffff0000u; rr[7] = t.f;
  }
  if (!do_hf){
    if (H == 0){
      uint4 ov;
      unsigned p[8];
      #pragma unroll
      for (int i = 0; i < 8; ++i) p[i] = f2bf(fmaxf(acc[i] + rr[i], 0.f));
      ov.x = p[0] | (p[1] << 16); ov.y = p[2] | (p[3] << 16);
      ov.z = p[4] | (p[5] << 16); ov.w = p[6] | (p[7] << 16);
      *(uint4*)(outb + (size_t)d * 256 + c * 8) = ov;
    }
  } else {
    #pragma unroll
    for (int i = 0; i < 8; ++i){
      float o = acc[i] + rr[i];
      o += __shfl_xor(o, 8);
      o += __shfl_xor(o, 16);
      acc[i] = o;
    }
    if (lane < 8){
      uint4 ov;
      unsigned p[8];
      #pragma unroll
      for (int i = 0; i < 8; ++i) p[i] = f2bf(0.25f * acc[i]);
      ov.x = p[0] | (p[1] << 16); ov.y = p[2] | (p[3] << 16);
      ov.z = p[4] | (p[5] << 16); ov.w = p[6] | (p[7] << 16);
      *(uint4*)(hf + (size_t)d * 64 + lane * 8) = ov;
    }
  }
}

// ---------------- MFMA edge MLP: 1 wave = 16 edges/tile -----------------------
__global__ __launch_bounds__(256) void edge_mlp_mfma(
    const u16* __restrict__ hfb,
    const int* __restrict__ src, const int* __restrict__ dst,
    const u16* __restrict__ Wm1, const u16* __restrict__ bm1,
    const u16* __restrict__ Wm2, const u16* __restrict__ bm2,
    void* __restrict__ out, int E, const int* __restrict__ flag)
{
  const int lane = threadIdx.x & 63;
  const int m = lane & 15;
  const int q = lane >> 4;
  const int is_f32 = *flag;

  bf16x8 bfr[4][2];
  #pragma unroll
  for (int t = 0; t < 4; ++t)
    #pragma unroll
    for (int ks = 0; ks < 2; ++ks)
      #pragma unroll
      for (int j = 0; j < 8; ++j)
        bfr[t][ks][j] = (short)Wm1[(size_t)(ks * 32 + q * 8 + j) * 64 + t * 16 + m];

  float b1v[4], w2v[4];
  #pragma unroll
  for (int t = 0; t < 4; ++t){
    b1v[t] = bf2f(bm1[t * 16 + m]);
    w2v[t] = bf2f(Wm2[t * 16 + m]);
  }
  const float b2 = bf2f(bm2[0]);

  const int wid = blockIdx.x * 4 + (threadIdx.x >> 6);
  const int nw  = gridDim.x * 4;
  for (int e0 = wid * 16; e0 < E; e0 += nw * 16){
    int e = e0 + m; if (e >= E) e = E - 1;
    const int s = src[e], d = dst[e];
    const u16* ps = hfb + (size_t)s * 64;
    const u16* pd = hfb + (size_t)d * 64;
    bf16x8 af[2];
    #pragma unroll
    for (int ks = 0; ks < 2; ++ks){
      bf16x8 vs = *(const bf16x8*)(ps + ks * 32 + q * 8);
      bf16x8 vd = *(const bf16x8*)(pd + ks * 32 + q * 8);
      #pragma unroll
      for (int j = 0; j < 8; ++j)
        af[ks][j] = (short)f2bf(fabsf(bf2f((u16)vs[j]) - bf2f((u16)vd[j])));
    }
    f32x4 acc[4];
    #pragma unroll
    for (int t = 0; t < 4; ++t) acc[t] = (f32x4){0.f, 0.f, 0.f, 0.f};
    #pragma unroll
    for (int ks = 0; ks < 2; ++ks)
      #pragma unroll
      for (int t = 0; t < 4; ++t)
        acc[t] = __builtin_amdgcn_mfma_f32_16x16x32_bf16(af[ks], bfr[t][ks], acc[t], 0, 0, 0);
    #pragma unroll
    for (int r = 0; r < 4; ++r){
      float p = 0.f;
      #pragma unroll
      for (int t = 0; t < 4; ++t)
        p += fmaxf(acc[t][r] + b1v[t], 0.f) * w2v[t];
      #pragma unroll
      for (int mm = 1; mm < 16; mm <<= 1) p += __shfl_xor(p, mm);
      int er = e0 + q * 4 + r;
      if (m == 0 && er < E){
        float sc = 1.f / (1.f + __expf(-(p + b2)));
        if (is_f32) ((float*)out)[er] = sc;
        else        ((u16*)out)[er]   = f2bf(sc);
      }
    }
  }
}

extern "C" void kernel_launch(void* const* d_in, const int* in_sizes, int n_in,
                              void* d_out, int out_size, void* d_ws, size_t ws_size,
                              hipStream_t stream)
{
  const int* src = (const int*)d_in[1];
  const int* dst = (const int*)d_in[2];

  const int N = in_sizes[0] / 128;
  const int E = in_sizes[1];

  char* p = (char*)d_ws;
  auto alloc = [&](size_t bytes) -> char* {
    char* r = p; p += (bytes + 255) & ~(size_t)255; return r;
  };
  int* flag   = (int*)  alloc(4);
  u16* hc     = (u16*)  alloc((size_t)N * 128 * 2);
  u16* FT     = (u16*)  alloc((size_t)N * 256 * 2);
  u16* XA     = (u16*)  alloc((size_t)N * 256 * 2);
  u16* XB     = (u16*)  alloc((size_t)N * 256 * 2);
  float* el   = (float*)alloc((size_t)N * 4 * 4);
  float* er   = (float*)alloc((size_t)N * 4 * 4);
  u16* hfb    = (u16*)  alloc((size_t)N * 64 * 2);
  int* rowptr = (int*)  alloc((size_t)(N + 1) * 4);
  int* cursor = (int*)  alloc((size_t)N * 4);
  int* csr    = (int*)  alloc((size_t)E * 4);
  int* bsums  = (int*)  alloc(1024);
  u16* WT1    = (u16*)  alloc(128 * 256 * 2);
  u16* WTr1   = (u16*)  alloc(128 * 256 * 2);
  u16* WT2    = (u16*)  alloc(256 * 256 * 2);
  u16* WT3    = (u16*)  alloc(256 * 256 * 2);
  u16* al1c   = (u16*)  alloc(256 * 2);
  u16* ar1c   = (u16*)  alloc(256 * 2);
  u16* al2c   = (u16*)  alloc(256 * 2);
  u16* ar2c   = (u16*)  alloc(256 * 2);
  u16* al3c   = (u16*)  alloc(256 * 2);
  u16* ar3c   = (u16*)  alloc(256 * 2);
  u16* Wm1c   = (u16*)  alloc(4096 * 2);
  u16* bm1c   = (u16*)  alloc(64 * 2);
  u16* Wm2c   = (u16*)  alloc(64 * 2);
  u16* bm2c   = (u16*)  alloc(2);

  const int nb = (N + 255) / 256;
  const int ge = (E + 255) / 256;

  // dtype sniff + canonicalize
  k_sniff<<<1, 256, 0, stream>>>((const u16*)d_in[0], flag);
  k_canon<<<(N * 128 + 255) / 256, 256, 0, stream>>>(d_in[0], hc, N * 128, flag);
  {
    Canon10 c;
    c.e[0] = {d_in[5],  al1c, 256};  c.e[1] = {d_in[6],  ar1c, 256};
    c.e[2] = {d_in[8],  al2c, 256};  c.e[3] = {d_in[9],  ar2c, 256};
    c.e[4] = {d_in[11], al3c, 256};  c.e[5] = {d_in[12], ar3c, 256};
    c.e[6] = {d_in[13], Wm1c, 4096}; c.e[7] = {d_in[14], bm1c, 64};
    c.e[8] = {d_in[15], Wm2c, 64};   c.e[9] = {d_in[16], bm2c, 1};
    dim3 g((4096 + 255) / 256, 10);
    k_canon10<<<g, 256, 0, stream>>>(c, flag);
  }
  {
    CanonW4 c;
    c.e[0] = {d_in[3],  WT1,  128};  c.e[1] = {d_in[4],  WTr1, 128};
    c.e[2] = {d_in[7],  WT2,  256};  c.e[3] = {d_in[10], WT3,  256};
    dim3 g(256, 4);
    k_canonw<<<g, 256, 0, stream>>>(c, flag);
  }

  // CSR by dst
  k_zero<<<nb, 256, 0, stream>>>(cursor, N);
  k_hist<<<ge, 256, 0, stream>>>(dst, cursor, E);
  k_scan1<<<nb, 256, 0, stream>>>(cursor, rowptr, bsums, N);
  k_scan2<<<1, 256, 0, stream>>>(bsums, nb);
  k_scan3<<<nb, 256, 0, stream>>>(rowptr, bsums, cursor, N);
  k_scatter<<<ge, 256, 0, stream>>>(src, dst, cursor, csr, E);

  const int gA = (N + 127) / 128;
  const int gG = (N + 3) / 4;
  // layer 1
  mfma_gemm_attn2<<<gA, 256, 0, stream>>>(hc, WT1, FT, al1c, ar1c, el, er, N, 128);
  mfma_gemm2<<<gA, 256, 0, stream>>>(hc, WTr1, XA, N, 128);
  aggregate4<<<gG, 256, 0, stream>>>(FT, el, er, rowptr, csr, XA, XB, nullptr, 0, N);
  // layer 2
  mfma_gemm_attn2<<<gA, 256, 0, stream>>>(XB, WT2, FT, al2c, ar2c, el, er, N, 256);
  aggregate4<<<gG, 256, 0, stream>>>(FT, el, er, rowptr, csr, XB, XA, nullptr, 0, N);
  // layer 3 (fused head-mean -> hf bf16)
  mfma_gemm_attn2<<<gA, 256, 0, stream>>>(XA, WT3, FT, al3c, ar3c, el, er, N, 256);
  aggregate4<<<gG, 256, 0, stream>>>(FT, el, er, rowptr, csr, XA, nullptr, hfb, 1, N);
  // edge MLP (MFMA)
  edge_mlp_mfma<<<2048, 256, 0, stream>>>(hfb, src, dst, Wm1c, bm1c, Wm2c, bm2c,
                                          d_out, E, flag);
}